// Round 1
// baseline (825.468 us; speedup 1.0000x reference)
//
#include <hip/hip_runtime.h>
#include <math.h>

// ---------------------------------------------------------------------------
// GCN (EdgeConv x3 + classifier + log_softmax) on MI355X.
// Decomposition:
//   out[n] = deg[n]*(ai[n]+b) + aj[n] + sum_{in-edges e} aj[src[e]] + eagg[n]@We^T
// where ai = x@Wi^T, aj = x@Wj^T, eagg[n] = sum of edge_attr over in-edges
// (computed ONCE, reused by all 3 layers), deg = in-degree + 1 (self loop).
// Per layer: node-local GEMM (LDS-staged W) -> CSR gather (deterministic).
// Final layer fuses 32->4 classifier + log_softmax via wave reduction.
// ---------------------------------------------------------------------------

static inline size_t align256(size_t x) { return (x + 255) & ~size_t(255); }

// ---- CSR build ------------------------------------------------------------

__global__ __launch_bounds__(256) void build_count(
    const int* __restrict__ ei, const float* __restrict__ ea,
    int* __restrict__ count, int* __restrict__ pos, float* __restrict__ eagg,
    int E)
{
    int e = blockIdx.x * 256 + threadIdx.x;
    if (e >= E) return;
    int d = ei[E + e];                    // dst
    pos[e] = atomicAdd(&count[d], 1);
    atomicAdd(&eagg[d * 3 + 0], ea[e * 3 + 0]);
    atomicAdd(&eagg[d * 3 + 1], ea[e * 3 + 1]);
    atomicAdd(&eagg[d * 3 + 2], ea[e * 3 + 2]);
}

// single-block exclusive scan: rowstart[0]=0, rowstart[i+1]=sum(count[0..i])
__global__ __launch_bounds__(1024) void scan_kernel(
    const int* __restrict__ count, int* __restrict__ rowstart, int n)
{
    __shared__ int tmp[1024];
    int tid = threadIdx.x;
    int carry = 0;
    for (int base = 0; base < n; base += 1024) {
        int i = base + tid;
        int v = (i < n) ? count[i] : 0;
        tmp[tid] = v;
        __syncthreads();
        for (int off = 1; off < 1024; off <<= 1) {
            int t = (tid >= off) ? tmp[tid - off] : 0;
            __syncthreads();
            tmp[tid] += t;
            __syncthreads();
        }
        if (i < n) rowstart[i + 1] = carry + tmp[tid];
        carry += tmp[1023];
        __syncthreads();
    }
    if (tid == 0) rowstart[0] = 0;
}

__global__ __launch_bounds__(256) void csr_scatter(
    const int* __restrict__ ei, const int* __restrict__ pos,
    const int* __restrict__ rowstart, int* __restrict__ csr_src, int E)
{
    int e = blockIdx.x * 256 + threadIdx.x;
    if (e >= E) return;
    int d = ei[E + e];
    csr_src[rowstart[d] + pos[e]] = ei[e];   // src
}

// ---- node-local GEMM: base & aj -------------------------------------------
// W layout: [FOUT][2*FIN+3] row-major (Wi | Wj | We per row).
// LDS-staged W^T (padded stride FOUT+1 -> conflict-free: (FOUT+1)%32==1).

template <int FIN, int FOUT>
__global__ __launch_bounds__(256) void node_linear(
    const float* __restrict__ x, const float* __restrict__ W,
    const float* __restrict__ b, const float* __restrict__ eagg,
    const int* __restrict__ count, float* __restrict__ basebuf,
    float* __restrict__ ajbuf, int n_nodes)
{
    constexpr int WROW = 2 * FIN + 3;
    constexpr int PAD  = FOUT + 1;
    __shared__ float sW[FIN * PAD];

    const int tid = threadIdx.x;
    constexpr int NPB = 256 / FOUT;          // nodes per block
    const int c = tid % FOUT;
    const int n = blockIdx.x * NPB + tid / FOUT;

    // phase A: stage Wi^T  (sW[k*PAD+c] = W[c][k])
    for (int idx = tid; idx < FIN * FOUT; idx += 256) {
        int cc = idx / FIN, kk = idx % FIN;
        sW[kk * PAD + cc] = W[cc * WROW + kk];
    }
    __syncthreads();

    float ai = 0.f;
    if (n < n_nodes) {
        #pragma unroll 4
        for (int k = 0; k < FIN; ++k) ai += x[n * FIN + k] * sW[k * PAD + c];
    }
    __syncthreads();

    // phase B: stage Wj^T
    for (int idx = tid; idx < FIN * FOUT; idx += 256) {
        int cc = idx / FIN, kk = idx % FIN;
        sW[kk * PAD + cc] = W[cc * WROW + FIN + kk];
    }
    __syncthreads();

    if (n >= n_nodes) return;
    float aj = 0.f;
    #pragma unroll 4
    for (int k = 0; k < FIN; ++k) aj += x[n * FIN + k] * sW[k * PAD + c];

    float we = W[c * WROW + 2 * FIN + 0] * eagg[n * 3 + 0]
             + W[c * WROW + 2 * FIN + 1] * eagg[n * 3 + 1]
             + W[c * WROW + 2 * FIN + 2] * eagg[n * 3 + 2];
    float deg = (float)(count[n] + 1);       // +1 self loop
    basebuf[n * FOUT + c] = deg * (ai + b[c]) + aj + we;
    ajbuf[n * FOUT + c]   = aj;
}

// ---- CSR gather: h[n] = relu?(base[n] + sum aj[src]) ----------------------
// one wave per node; lane covers FOUT/64 channels

template <int FOUT, bool RELU>
__global__ __launch_bounds__(256) void gather_kernel(
    const float* __restrict__ basebuf, const float* __restrict__ ajbuf,
    const int* __restrict__ rowstart, const int* __restrict__ csr_src,
    float* __restrict__ h, int n_nodes)
{
    constexpr int CPL = FOUT / 64;
    int wave = threadIdx.x >> 6, lane = threadIdx.x & 63;
    int n = blockIdx.x * 4 + wave;
    if (n >= n_nodes) return;

    float acc[CPL];
    #pragma unroll
    for (int j = 0; j < CPL; ++j) acc[j] = basebuf[n * FOUT + j * 64 + lane];

    int s0 = rowstart[n], s1 = rowstart[n + 1];
    for (int i = s0; i < s1; ++i) {
        int s = csr_src[i];                  // wave-uniform
        #pragma unroll
        for (int j = 0; j < CPL; ++j) acc[j] += ajbuf[s * FOUT + j * 64 + lane];
    }
    #pragma unroll
    for (int j = 0; j < CPL; ++j) {
        float v = acc[j];
        if (RELU) v = fmaxf(v, 0.f);
        h[n * FOUT + j * 64 + lane] = v;
    }
}

// ---- final layer: gather(32) + classifier(32->4) + log_softmax ------------

__global__ __launch_bounds__(256) void gather_final(
    const float* __restrict__ basebuf, const float* __restrict__ ajbuf,
    const int* __restrict__ rowstart, const int* __restrict__ csr_src,
    const float* __restrict__ Wc, const float* __restrict__ bc,
    float* __restrict__ out, int n_nodes)
{
    int wave = threadIdx.x >> 6, lane = threadIdx.x & 63;
    int n = blockIdx.x * 4 + wave;
    if (n >= n_nodes) return;

    float acc = 0.f;
    if (lane < 32) acc = basebuf[n * 32 + lane];
    int s0 = rowstart[n], s1 = rowstart[n + 1];
    for (int i = s0; i < s1; ++i) {
        int s = csr_src[i];
        if (lane < 32) acc += ajbuf[s * 32 + lane];
    }
    // acc = h3[n][lane] on lanes 0..31, 0 elsewhere
    float logits[4];
    #pragma unroll
    for (int j = 0; j < 4; ++j) {
        float v = (lane < 32) ? acc * Wc[j * 32 + lane] : 0.f;
        v += __shfl_down(v, 32);
        v += __shfl_down(v, 16);
        v += __shfl_down(v, 8);
        v += __shfl_down(v, 4);
        v += __shfl_down(v, 2);
        v += __shfl_down(v, 1);
        logits[j] = v;                       // valid on lane 0
    }
    if (lane == 0) {
        float l0 = logits[0] + bc[0], l1 = logits[1] + bc[1];
        float l2 = logits[2] + bc[2], l3 = logits[3] + bc[3];
        float m = fmaxf(fmaxf(l0, l1), fmaxf(l2, l3));
        float lse = logf(expf(l0 - m) + expf(l1 - m) + expf(l2 - m) + expf(l3 - m));
        float4 o = make_float4(l0 - m - lse, l1 - m - lse, l2 - m - lse, l3 - m - lse);
        *(float4*)(out + n * 4) = o;
    }
}

// ---------------------------------------------------------------------------

extern "C" void kernel_launch(void* const* d_in, const int* in_sizes, int n_in,
                              void* d_out, int out_size, void* d_ws, size_t ws_size,
                              hipStream_t stream)
{
    const float* x    = (const float*)d_in[0];
    const int*   ei   = (const int*)  d_in[1];
    const float* ea   = (const float*)d_in[2];
    const float* W1   = (const float*)d_in[3];
    const float* b1   = (const float*)d_in[4];
    const float* W2   = (const float*)d_in[5];
    const float* b2   = (const float*)d_in[6];
    const float* W3   = (const float*)d_in[7];
    const float* b3   = (const float*)d_in[8];
    const float* Wc   = (const float*)d_in[9];
    const float* bc   = (const float*)d_in[10];
    float* out = (float*)d_out;

    const int N = in_sizes[0] / 3;
    const int E = in_sizes[1] / 2;

    char* ws = (char*)d_ws;
    size_t off = 0;
    int*   count    = (int*)(ws + off);  off = align256(off + (size_t)N * 4);
    float* eagg     = (float*)(ws + off); off = align256(off + (size_t)N * 12);
    int*   pos      = (int*)(ws + off);  off = align256(off + (size_t)E * 4);
    int*   rowstart = (int*)(ws + off);  off = align256(off + (size_t)(N + 1) * 4);
    int*   csr_src  = (int*)(ws + off);  off = align256(off + (size_t)E * 4);
    float* ajbuf    = (float*)(ws + off); off = align256(off + (size_t)N * 128 * 4);
    float* basebuf  = (float*)(ws + off); off = align256(off + (size_t)N * 128 * 4);
    float* hbuf     = (float*)(ws + off); off = align256(off + (size_t)N * 128 * 4);
    (void)ws_size;

    hipMemsetAsync(count, 0, (size_t)N * 4, stream);
    hipMemsetAsync(eagg, 0, (size_t)N * 12, stream);

    const int eb = (E + 255) / 256;
    build_count<<<eb, 256, 0, stream>>>(ei, ea, count, pos, eagg, E);
    scan_kernel<<<1, 1024, 0, stream>>>(count, rowstart, N);
    csr_scatter<<<eb, 256, 0, stream>>>(ei, pos, rowstart, csr_src, E);

    // layer 1: 3 -> 128, relu
    node_linear<3, 128><<<(N + 1) / 2, 256, 0, stream>>>(x, W1, b1, eagg, count, basebuf, ajbuf, N);
    gather_kernel<128, true><<<(N + 3) / 4, 256, 0, stream>>>(basebuf, ajbuf, rowstart, csr_src, hbuf, N);

    // layer 2: 128 -> 64, relu
    node_linear<128, 64><<<(N + 3) / 4, 256, 0, stream>>>(hbuf, W2, b2, eagg, count, basebuf, ajbuf, N);
    gather_kernel<64, true><<<(N + 3) / 4, 256, 0, stream>>>(basebuf, ajbuf, rowstart, csr_src, hbuf, N);

    // layer 3: 64 -> 32, no relu; fused classifier + log_softmax
    node_linear<64, 32><<<(N + 7) / 8, 256, 0, stream>>>(hbuf, W3, b3, eagg, count, basebuf, ajbuf, N);
    gather_final<<<(N + 3) / 4, 256, 0, stream>>>(basebuf, ajbuf, rowstart, csr_src, Wc, bc, out, N);
}

// Round 2
// 602.754 us; speedup vs baseline: 1.3695x; 1.3695x over previous
//
#include <hip/hip_runtime.h>
#include <math.h>

// ---------------------------------------------------------------------------
// GCN (EdgeConv x3 + classifier + log_softmax) on MI355X.
//   out[n] = deg[n]*(ai[n]+b) + aj[n] + sum_{in-edges e} aj[src[e]] + eagg[n]@We^T
// R2: layers 2,3 use a register-blocked LDS GEMM producing P=[ai|aj]; the
// deg/bias/We epilogue is fused into the gather. Scan is 3-pass parallel.
// ---------------------------------------------------------------------------

static inline size_t align256(size_t x) { return (x + 255) & ~size_t(255); }

// ---- CSR build ------------------------------------------------------------

__global__ __launch_bounds__(256) void build_count(
    const int* __restrict__ ei, const float* __restrict__ ea,
    int* __restrict__ count, int* __restrict__ pos, float* __restrict__ eagg,
    int E)
{
    int e = blockIdx.x * 256 + threadIdx.x;
    if (e >= E) return;
    int d = ei[E + e];                    // dst
    pos[e] = atomicAdd(&count[d], 1);
    atomicAdd(&eagg[d * 3 + 0], ea[e * 3 + 0]);
    atomicAdd(&eagg[d * 3 + 1], ea[e * 3 + 1]);
    atomicAdd(&eagg[d * 3 + 2], ea[e * 3 + 2]);
}

// ---- 3-pass exclusive scan of count -> rowstart ---------------------------

__global__ __launch_bounds__(256) void scan_pass1(
    const int* __restrict__ count, int* __restrict__ rowstart,
    int* __restrict__ bsum, int n)
{
    __shared__ int sh[256];
    const int tid = threadIdx.x;
    const int base = blockIdx.x * 1024 + tid * 4;
    int v0 = 0, v1 = 0, v2 = 0, v3 = 0;
    if (base + 3 < n) {
        int4 c = *(const int4*)(count + base);
        v0 = c.x; v1 = c.y; v2 = c.z; v3 = c.w;
    } else {
        if (base + 0 < n) v0 = count[base + 0];
        if (base + 1 < n) v1 = count[base + 1];
        if (base + 2 < n) v2 = count[base + 2];
        if (base + 3 < n) v3 = count[base + 3];
    }
    int tsum = v0 + v1 + v2 + v3;
    sh[tid] = tsum;
    __syncthreads();
    for (int off = 1; off < 256; off <<= 1) {
        int t = (tid >= off) ? sh[tid - off] : 0;
        __syncthreads();
        sh[tid] += t;
        __syncthreads();
    }
    int excl = sh[tid] - tsum;
    int p0 = excl + v0, p1 = p0 + v1, p2 = p1 + v2, p3 = p2 + v3;
    if (base + 0 < n) rowstart[base + 1] = p0;
    if (base + 1 < n) rowstart[base + 2] = p1;
    if (base + 2 < n) rowstart[base + 3] = p2;
    if (base + 3 < n) rowstart[base + 4] = p3;
    if (tid == 255) bsum[blockIdx.x] = sh[255];
}

__global__ __launch_bounds__(64) void scan_pass2(
    const int* __restrict__ bsum, int* __restrict__ bexcl, int nb)
{
    int lane = threadIdx.x;
    int own = (lane < nb) ? bsum[lane] : 0;
    int x = own;
    for (int off = 1; off < 64; off <<= 1) {
        int t = __shfl_up(x, off);
        if (lane >= off) x += t;
    }
    bexcl[lane] = x - own;
}

__global__ __launch_bounds__(256) void scan_pass3(
    int* __restrict__ rowstart, const int* __restrict__ bexcl, int n)
{
    int j = blockIdx.x * 256 + threadIdx.x;
    if (j > n) return;
    if (j == 0) { rowstart[0] = 0; return; }
    int b = (j - 1) >> 10;
    if (b > 0) rowstart[j] += bexcl[b];
}

__global__ __launch_bounds__(256) void csr_scatter(
    const int* __restrict__ ei, const int* __restrict__ pos,
    const int* __restrict__ rowstart, int* __restrict__ csr_src, int E)
{
    int e = blockIdx.x * 256 + threadIdx.x;
    if (e >= E) return;
    int d = ei[E + e];
    csr_src[rowstart[d] + pos[e]] = ei[e];   // src
}

// ---- layer-1 node linear (K=3, trivial) -----------------------------------

template <int FIN, int FOUT>
__global__ __launch_bounds__(256) void node_linear(
    const float* __restrict__ x, const float* __restrict__ W,
    const float* __restrict__ b, const float* __restrict__ eagg,
    const int* __restrict__ count, float* __restrict__ basebuf,
    float* __restrict__ ajbuf, int n_nodes)
{
    constexpr int WROW = 2 * FIN + 3;
    constexpr int PAD  = FOUT + 1;
    __shared__ float sW[FIN * PAD];

    const int tid = threadIdx.x;
    constexpr int NPB = 256 / FOUT;
    const int c = tid % FOUT;
    const int n = blockIdx.x * NPB + tid / FOUT;

    for (int idx = tid; idx < FIN * FOUT; idx += 256) {
        int cc = idx / FIN, kk = idx % FIN;
        sW[kk * PAD + cc] = W[cc * WROW + kk];
    }
    __syncthreads();

    float ai = 0.f;
    if (n < n_nodes) {
        #pragma unroll
        for (int k = 0; k < FIN; ++k) ai += x[n * FIN + k] * sW[k * PAD + c];
    }
    __syncthreads();

    for (int idx = tid; idx < FIN * FOUT; idx += 256) {
        int cc = idx / FIN, kk = idx % FIN;
        sW[kk * PAD + cc] = W[cc * WROW + FIN + kk];
    }
    __syncthreads();

    if (n >= n_nodes) return;
    float aj = 0.f;
    #pragma unroll
    for (int k = 0; k < FIN; ++k) aj += x[n * FIN + k] * sW[k * PAD + c];

    float we = W[c * WROW + 2 * FIN + 0] * eagg[n * 3 + 0]
             + W[c * WROW + 2 * FIN + 1] * eagg[n * 3 + 1]
             + W[c * WROW + 2 * FIN + 2] * eagg[n * 3 + 2];
    float deg = (float)(count[n] + 1);
    basebuf[n * FOUT + c] = deg * (ai + b[c]) + aj + we;
    ajbuf[n * FOUT + c]   = aj;
}

// ---- register-blocked GEMM: P = x @ [Wi^T | Wj^T] -------------------------
// Block tile: 64 nodes x NCB columns (NCB=64). 256 threads, 4x4 micro-tile.
// LDS layouts are k-chunked so all fragment reads are ds_read_b128 with
// <=2-way bank aliasing (free):
//   sX[(k>>2)*64  + m]*4 + (k&3)   (element (m,k))
//   sW[(k>>2)*NCB + j]*4 + (k&3)   (element (j,k), j = column within block)
// Column j maps to global column jg = blockIdx.y*NCB + j:
//   jg <  FOUT: ai channel jg   (Wi row jg)
//   jg >= FOUT: aj channel jg-FOUT (Wj row)

template <int FIN, int NCB, int FOUT>
__global__ __launch_bounds__(256) void gemm_tile(
    const float* __restrict__ x, const float* __restrict__ W,
    float* __restrict__ P, int n_nodes)
{
    constexpr int NC = 2 * FOUT;
    constexpr int WROW = 2 * FIN + 3;
    __shared__ float sX[64 * FIN];
    __shared__ float sW[NCB * FIN];

    const int tid = threadIdx.x;
    const int tx = tid & 15;
    const int ty = tid >> 4;
    const int mbase = blockIdx.x * 64;
    const int jbase = blockIdx.y * NCB;

    // stage x tile (k-chunked layout)
    constexpr int XT = 16 * FIN;           // float4 count
    for (int t = tid; t < XT; t += 256) {
        int r = t & 63, ch = t >> 6;
        int gn = mbase + r;
        float4 v = make_float4(0.f, 0.f, 0.f, 0.f);
        if (gn < n_nodes) v = *(const float4*)(x + (size_t)gn * FIN + ch * 4);
        *(float4*)(sX + (ch * 64 + r) * 4) = v;
    }
    // stage W' tile (k-chunked layout)
    for (int t = tid; t < NCB * FIN; t += 256) {
        int j = t / FIN, k = t % FIN;
        int jg = jbase + j;
        float w = (jg < FOUT) ? W[jg * WROW + k] : W[(jg - FOUT) * WROW + FIN + k];
        sW[((k >> 2) * NCB + j) * 4 + (k & 3)] = w;
    }
    __syncthreads();

    float acc[4][4];
    #pragma unroll
    for (int i = 0; i < 4; ++i)
        #pragma unroll
        for (int jj = 0; jj < 4; ++jj) acc[i][jj] = 0.f;

    #pragma unroll 2
    for (int k0 = 0; k0 < FIN; k0 += 4) {
        float4 a[4], bb[4];
        #pragma unroll
        for (int i = 0; i < 4; ++i)
            a[i] = *(const float4*)(sX + ((k0 >> 2) * 64 + (ty * 4 + i)) * 4);
        #pragma unroll
        for (int i = 0; i < 4; ++i)
            bb[i] = *(const float4*)(sW + ((k0 >> 2) * NCB + (tx + 16 * i)) * 4);
        #pragma unroll
        for (int mi = 0; mi < 4; ++mi)
            #pragma unroll
            for (int ji = 0; ji < 4; ++ji)
                acc[mi][ji] += a[mi].x * bb[ji].x + a[mi].y * bb[ji].y
                             + a[mi].z * bb[ji].z + a[mi].w * bb[ji].w;
    }

    #pragma unroll
    for (int mi = 0; mi < 4; ++mi) {
        int gn = mbase + ty * 4 + mi;
        if (gn >= n_nodes) continue;
        #pragma unroll
        for (int ji = 0; ji < 4; ++ji)
            P[(size_t)gn * NC + jbase + tx + 16 * ji] = acc[mi][ji];
    }
}

// ---- layer-1 gather (reads basebuf/ajbuf) ---------------------------------

template <int FOUT, bool RELU>
__global__ __launch_bounds__(256) void gather_kernel(
    const float* __restrict__ basebuf, const float* __restrict__ ajbuf,
    const int* __restrict__ rowstart, const int* __restrict__ csr_src,
    float* __restrict__ h, int n_nodes)
{
    constexpr int CPL = FOUT / 64;
    int wave = threadIdx.x >> 6, lane = threadIdx.x & 63;
    int n = blockIdx.x * 4 + wave;
    if (n >= n_nodes) return;

    float acc[CPL];
    #pragma unroll
    for (int j = 0; j < CPL; ++j) acc[j] = basebuf[n * FOUT + j * 64 + lane];

    int s0 = rowstart[n], s1 = rowstart[n + 1];
    for (int i = s0; i < s1; ++i) {
        int s = csr_src[i];
        #pragma unroll
        for (int j = 0; j < CPL; ++j) acc[j] += ajbuf[(size_t)s * FOUT + j * 64 + lane];
    }
    #pragma unroll
    for (int j = 0; j < CPL; ++j) {
        float v = acc[j];
        if (RELU) v = fmaxf(v, 0.f);
        h[(size_t)n * FOUT + j * 64 + lane] = v;
    }
}

// ---- gather with fused epilogue (layers 2): P=[ai|aj], FOUT=64 ------------

template <int FOUT, bool RELU>
__global__ __launch_bounds__(256) void gather_epi(
    const float* __restrict__ P, const float* __restrict__ W,
    const float* __restrict__ bvec, const float* __restrict__ eagg,
    const int* __restrict__ count, const int* __restrict__ rowstart,
    const int* __restrict__ csr_src, float* __restrict__ h,
    int n_nodes, int WROW)
{
    constexpr int NC = 2 * FOUT;
    int wave = threadIdx.x >> 6, lane = threadIdx.x & 63;
    int n = blockIdx.x * 4 + wave;
    if (n >= n_nodes) return;

    const float* Pr = P + (size_t)n * NC;
    float ai = Pr[lane];
    float aj = Pr[FOUT + lane];
    int wo = lane * WROW + (WROW - 3);
    float we = W[wo] * eagg[n * 3] + W[wo + 1] * eagg[n * 3 + 1] + W[wo + 2] * eagg[n * 3 + 2];
    float deg = (float)(count[n] + 1);
    float acc = deg * (ai + bvec[lane]) + aj + we;

    int s0 = rowstart[n], s1 = rowstart[n + 1];
    for (int i = s0; i < s1; ++i) {
        int s = csr_src[i];
        acc += P[(size_t)s * NC + FOUT + lane];
    }
    if (RELU) acc = fmaxf(acc, 0.f);
    h[(size_t)n * FOUT + lane] = acc;
}

// ---- final: gather(32)+epilogue + classifier + log_softmax ----------------

__global__ __launch_bounds__(256) void gather_final_epi(
    const float* __restrict__ P, const float* __restrict__ W,
    const float* __restrict__ bvec, const float* __restrict__ eagg,
    const int* __restrict__ count, const int* __restrict__ rowstart,
    const int* __restrict__ csr_src, const float* __restrict__ Wc,
    const float* __restrict__ bc, float* __restrict__ out,
    int n_nodes, int WROW)
{
    int wave = threadIdx.x >> 6, lane = threadIdx.x & 63;
    int n = blockIdx.x * 4 + wave;
    if (n >= n_nodes) return;

    float acc = 0.f;
    if (lane < 32) {
        const float* Pr = P + (size_t)n * 64;
        float ai = Pr[lane];
        float aj = Pr[32 + lane];
        int wo = lane * WROW + (WROW - 3);
        float we = W[wo] * eagg[n * 3] + W[wo + 1] * eagg[n * 3 + 1] + W[wo + 2] * eagg[n * 3 + 2];
        float deg = (float)(count[n] + 1);
        acc = deg * (ai + bvec[lane]) + aj + we;
    }
    int s0 = rowstart[n], s1 = rowstart[n + 1];
    for (int i = s0; i < s1; ++i) {
        int s = csr_src[i];
        if (lane < 32) acc += P[(size_t)s * 64 + 32 + lane];
    }
    float logits[4];
    #pragma unroll
    for (int j = 0; j < 4; ++j) {
        float v = (lane < 32) ? acc * Wc[j * 32 + lane] : 0.f;
        v += __shfl_down(v, 32);
        v += __shfl_down(v, 16);
        v += __shfl_down(v, 8);
        v += __shfl_down(v, 4);
        v += __shfl_down(v, 2);
        v += __shfl_down(v, 1);
        logits[j] = v;
    }
    if (lane == 0) {
        float l0 = logits[0] + bc[0], l1 = logits[1] + bc[1];
        float l2 = logits[2] + bc[2], l3 = logits[3] + bc[3];
        float m = fmaxf(fmaxf(l0, l1), fmaxf(l2, l3));
        float lse = logf(expf(l0 - m) + expf(l1 - m) + expf(l2 - m) + expf(l3 - m));
        float4 o = make_float4(l0 - m - lse, l1 - m - lse, l2 - m - lse, l3 - m - lse);
        *(float4*)(out + n * 4) = o;
    }
}

// ---------------------------------------------------------------------------

extern "C" void kernel_launch(void* const* d_in, const int* in_sizes, int n_in,
                              void* d_out, int out_size, void* d_ws, size_t ws_size,
                              hipStream_t stream)
{
    const float* x    = (const float*)d_in[0];
    const int*   ei   = (const int*)  d_in[1];
    const float* ea   = (const float*)d_in[2];
    const float* W1   = (const float*)d_in[3];
    const float* b1   = (const float*)d_in[4];
    const float* W2   = (const float*)d_in[5];
    const float* b2   = (const float*)d_in[6];
    const float* W3   = (const float*)d_in[7];
    const float* b3   = (const float*)d_in[8];
    const float* Wc   = (const float*)d_in[9];
    const float* bc   = (const float*)d_in[10];
    float* out = (float*)d_out;

    const int N = in_sizes[0] / 3;
    const int E = in_sizes[1] / 2;

    char* ws = (char*)d_ws;
    size_t off = 0;
    int*   count    = (int*)(ws + off);   off = align256(off + (size_t)N * 4);
    float* eagg     = (float*)(ws + off); off = align256(off + (size_t)N * 12);
    int*   pos      = (int*)(ws + off);   off = align256(off + (size_t)E * 4);
    int*   rowstart = (int*)(ws + off);   off = align256(off + (size_t)(N + 1) * 4);
    int*   csr_src  = (int*)(ws + off);   off = align256(off + (size_t)E * 4);
    int*   bsum     = (int*)(ws + off);   off = align256(off + 256);
    int*   bexcl    = (int*)(ws + off);   off = align256(off + 256);
    float* bufA     = (float*)(ws + off); off = align256(off + (size_t)N * 128 * 4);
    float* bufB     = (float*)(ws + off); off = align256(off + (size_t)N * 128 * 4);
    float* bufC     = (float*)(ws + off); off = align256(off + (size_t)N * 128 * 4);
    (void)ws_size;

    hipMemsetAsync(count, 0, (size_t)N * 4, stream);
    hipMemsetAsync(eagg, 0, (size_t)N * 12, stream);

    const int eb = (E + 255) / 256;
    build_count<<<eb, 256, 0, stream>>>(ei, ea, count, pos, eagg, E);

    const int nb1 = (N + 1023) / 1024;
    scan_pass1<<<nb1, 256, 0, stream>>>(count, rowstart, bsum, N);
    scan_pass2<<<1, 64, 0, stream>>>(bsum, bexcl, nb1);
    scan_pass3<<<(N + 1 + 255) / 256, 256, 0, stream>>>(rowstart, bexcl, N);
    csr_scatter<<<eb, 256, 0, stream>>>(ei, pos, rowstart, csr_src, E);

    const int mt = (N + 63) / 64;

    // layer 1: 3 -> 128, relu (basebuf=bufA, ajbuf=bufB, h1=bufC)
    node_linear<3, 128><<<(N + 1) / 2, 256, 0, stream>>>(x, W1, b1, eagg, count, bufA, bufB, N);
    gather_kernel<128, true><<<(N + 3) / 4, 256, 0, stream>>>(bufA, bufB, rowstart, csr_src, bufC, N);

    // layer 2: 128 -> 64, relu  (P2 = bufA [N x 128], h2 = bufB [N x 64])
    gemm_tile<128, 64, 64><<<dim3(mt, 2), 256, 0, stream>>>(bufC, W2, bufA, N);
    gather_epi<64, true><<<(N + 3) / 4, 256, 0, stream>>>(bufA, W2, b2, eagg, count, rowstart, csr_src, bufB, N, 259);

    // layer 3: 64 -> 32  (P3 = bufA [N x 64]); fused classifier + log_softmax
    gemm_tile<64, 64, 32><<<dim3(mt, 1), 256, 0, stream>>>(bufB, W3, bufA, N);
    gather_final_epi<<<(N + 3) / 4, 256, 0, stream>>>(bufA, W3, b3, eagg, count, rowstart, csr_src, Wc, bc, out, N, 131);
}

// Round 3
// 463.484 us; speedup vs baseline: 1.7810x; 1.3005x over previous
//
#include <hip/hip_runtime.h>
#include <math.h>

// ---------------------------------------------------------------------------
// GCN (EdgeConv x3 + classifier + log_softmax) on MI355X.
//   out[n] = deg[n]*(ai[n]+b) + aj[n] + sum_{in-edges e} aj[src[e]] + We@eagg[n]
// R3: build_count does a single int atomic/edge (no fp32 eagg atomics);
// CSR stores (src, eid); eagg computed deterministically inside the layer-1
// gather; deg derived from rowstart. Layer-1 gather uses half-wave float4
// row loads (4x fewer VMEM instructions).
// ---------------------------------------------------------------------------

static inline size_t align256(size_t x) { return (x + 255) & ~size_t(255); }

// ---- CSR build ------------------------------------------------------------

__global__ __launch_bounds__(256) void build_count(
    const int* __restrict__ ei, int* __restrict__ count,
    int* __restrict__ pos, int E)
{
    int e = blockIdx.x * 256 + threadIdx.x;
    if (e >= E) return;
    pos[e] = atomicAdd(&count[ei[E + e]], 1);
}

// ---- 3-pass exclusive scan of count -> rowstart ---------------------------

__global__ __launch_bounds__(256) void scan_pass1(
    const int* __restrict__ count, int* __restrict__ rowstart,
    int* __restrict__ bsum, int n)
{
    __shared__ int sh[256];
    const int tid = threadIdx.x;
    const int base = blockIdx.x * 1024 + tid * 4;
    int v0 = 0, v1 = 0, v2 = 0, v3 = 0;
    if (base + 3 < n) {
        int4 c = *(const int4*)(count + base);
        v0 = c.x; v1 = c.y; v2 = c.z; v3 = c.w;
    } else {
        if (base + 0 < n) v0 = count[base + 0];
        if (base + 1 < n) v1 = count[base + 1];
        if (base + 2 < n) v2 = count[base + 2];
        if (base + 3 < n) v3 = count[base + 3];
    }
    int tsum = v0 + v1 + v2 + v3;
    sh[tid] = tsum;
    __syncthreads();
    for (int off = 1; off < 256; off <<= 1) {
        int t = (tid >= off) ? sh[tid - off] : 0;
        __syncthreads();
        sh[tid] += t;
        __syncthreads();
    }
    int excl = sh[tid] - tsum;
    int p0 = excl + v0, p1 = p0 + v1, p2 = p1 + v2, p3 = p2 + v3;
    if (base + 0 < n) rowstart[base + 1] = p0;
    if (base + 1 < n) rowstart[base + 2] = p1;
    if (base + 2 < n) rowstart[base + 3] = p2;
    if (base + 3 < n) rowstart[base + 4] = p3;
    if (tid == 255) bsum[blockIdx.x] = sh[255];
}

__global__ __launch_bounds__(64) void scan_pass2(
    const int* __restrict__ bsum, int* __restrict__ bexcl, int nb)
{
    int lane = threadIdx.x;
    int own = (lane < nb) ? bsum[lane] : 0;
    int x = own;
    for (int off = 1; off < 64; off <<= 1) {
        int t = __shfl_up(x, off);
        if (lane >= off) x += t;
    }
    bexcl[lane] = x - own;
}

__global__ __launch_bounds__(256) void scan_pass3(
    int* __restrict__ rowstart, const int* __restrict__ bexcl, int n)
{
    int j = blockIdx.x * 256 + threadIdx.x;
    if (j > n) return;
    if (j == 0) { rowstart[0] = 0; return; }
    int b = (j - 1) >> 10;
    if (b > 0) rowstart[j] += bexcl[b];
}

__global__ __launch_bounds__(256) void csr_scatter(
    const int* __restrict__ ei, const int* __restrict__ pos,
    const int* __restrict__ rowstart, int2* __restrict__ csr, int E)
{
    int e = blockIdx.x * 256 + threadIdx.x;
    if (e >= E) return;
    int d = ei[E + e];
    csr[rowstart[d] + pos[e]] = make_int2(ei[e], e);   // (src, edge id)
}

// ---- layer-1 node linear (K=3): pure ai/aj --------------------------------

template <int FIN, int FOUT>
__global__ __launch_bounds__(256) void node_linear(
    const float* __restrict__ x, const float* __restrict__ W,
    float* __restrict__ aibuf, float* __restrict__ ajbuf, int n_nodes)
{
    constexpr int WROW = 2 * FIN + 3;
    constexpr int PAD  = FOUT + 1;
    __shared__ float sWi[FIN * PAD];
    __shared__ float sWj[FIN * PAD];

    const int tid = threadIdx.x;
    constexpr int NPB = 256 / FOUT;
    const int c = tid % FOUT;
    const int n = blockIdx.x * NPB + tid / FOUT;

    for (int idx = tid; idx < FIN * FOUT; idx += 256) {
        int cc = idx / FIN, kk = idx % FIN;
        sWi[kk * PAD + cc] = W[cc * WROW + kk];
        sWj[kk * PAD + cc] = W[cc * WROW + FIN + kk];
    }
    __syncthreads();

    if (n >= n_nodes) return;
    float ai = 0.f, aj = 0.f;
    #pragma unroll
    for (int k = 0; k < FIN; ++k) {
        float xv = x[n * FIN + k];
        ai += xv * sWi[k * PAD + c];
        aj += xv * sWj[k * PAD + c];
    }
    aibuf[(size_t)n * FOUT + c] = ai;
    ajbuf[(size_t)n * FOUT + c] = aj;
}

// ---- register-blocked GEMM: P = x @ [Wi^T | Wj^T] -------------------------

template <int FIN, int NCB, int FOUT>
__global__ __launch_bounds__(256) void gemm_tile(
    const float* __restrict__ x, const float* __restrict__ W,
    float* __restrict__ P, int n_nodes)
{
    constexpr int NC = 2 * FOUT;
    constexpr int WROW = 2 * FIN + 3;
    __shared__ float sX[64 * FIN];
    __shared__ float sW[NCB * FIN];

    const int tid = threadIdx.x;
    const int tx = tid & 15;
    const int ty = tid >> 4;
    const int mbase = blockIdx.x * 64;
    const int jbase = blockIdx.y * NCB;

    constexpr int XT = 16 * FIN;           // float4 count
    for (int t = tid; t < XT; t += 256) {
        int r = t & 63, ch = t >> 6;
        int gn = mbase + r;
        float4 v = make_float4(0.f, 0.f, 0.f, 0.f);
        if (gn < n_nodes) v = *(const float4*)(x + (size_t)gn * FIN + ch * 4);
        *(float4*)(sX + (ch * 64 + r) * 4) = v;
    }
    for (int t = tid; t < NCB * FIN; t += 256) {
        int j = t / FIN, k = t % FIN;
        int jg = jbase + j;
        float w = (jg < FOUT) ? W[jg * WROW + k] : W[(jg - FOUT) * WROW + FIN + k];
        sW[((k >> 2) * NCB + j) * 4 + (k & 3)] = w;
    }
    __syncthreads();

    float acc[4][4];
    #pragma unroll
    for (int i = 0; i < 4; ++i)
        #pragma unroll
        for (int jj = 0; jj < 4; ++jj) acc[i][jj] = 0.f;

    #pragma unroll 2
    for (int k0 = 0; k0 < FIN; k0 += 4) {
        float4 a[4], bb[4];
        #pragma unroll
        for (int i = 0; i < 4; ++i)
            a[i] = *(const float4*)(sX + ((k0 >> 2) * 64 + (ty * 4 + i)) * 4);
        #pragma unroll
        for (int i = 0; i < 4; ++i)
            bb[i] = *(const float4*)(sW + ((k0 >> 2) * NCB + (tx + 16 * i)) * 4);
        #pragma unroll
        for (int mi = 0; mi < 4; ++mi)
            #pragma unroll
            for (int ji = 0; ji < 4; ++ji)
                acc[mi][ji] += a[mi].x * bb[ji].x + a[mi].y * bb[ji].y
                             + a[mi].z * bb[ji].z + a[mi].w * bb[ji].w;
    }

    #pragma unroll
    for (int mi = 0; mi < 4; ++mi) {
        int gn = mbase + ty * 4 + mi;
        if (gn >= n_nodes) continue;
        #pragma unroll
        for (int ji = 0; ji < 4; ++ji)
            P[(size_t)gn * NC + jbase + tx + 16 * ji] = acc[mi][ji];
    }
}

// ---- layer-1 gather: half-wave float4 rows + fused epilogue + eagg --------
// lanes 0-31 take even edges, 32-63 odd edges; each lane loads one float4 of
// the 128-float aj row; halves combined with shfl_xor(32).

__global__ __launch_bounds__(256) void gather1(
    const float* __restrict__ aibuf, const float* __restrict__ ajbuf,
    const int* __restrict__ rowstart, const int2* __restrict__ csr,
    const float* __restrict__ ea, const float* __restrict__ W1,
    const float* __restrict__ b1, float* __restrict__ eagg,
    float* __restrict__ h, int n_nodes)
{
    int wave = threadIdx.x >> 6, lane = threadIdx.x & 63;
    int n = blockIdx.x * 4 + wave;
    if (n >= n_nodes) return;

    int s0 = rowstart[n], s1 = rowstart[n + 1];
    int half = lane >> 5;
    int l = lane & 31;

    float4 acc = make_float4(0.f, 0.f, 0.f, 0.f);
    float ex = 0.f, ey = 0.f, ez = 0.f;
    for (int i = s0 + half; i < s1; i += 2) {
        int2 c = csr[i];
        float4 v = *(const float4*)(ajbuf + (size_t)c.x * 128 + l * 4);
        acc.x += v.x; acc.y += v.y; acc.z += v.z; acc.w += v.w;
        const float* ep = ea + (size_t)c.y * 3;
        ex += ep[0]; ey += ep[1]; ez += ep[2];
    }
    acc.x += __shfl_xor(acc.x, 32);
    acc.y += __shfl_xor(acc.y, 32);
    acc.z += __shfl_xor(acc.z, 32);
    acc.w += __shfl_xor(acc.w, 32);
    ex += __shfl_xor(ex, 32);
    ey += __shfl_xor(ey, 32);
    ez += __shfl_xor(ez, 32);

    if (lane < 32) {
        float deg = (float)(s1 - s0 + 1);
        float4 a4 = *(const float4*)(aibuf + (size_t)n * 128 + lane * 4);
        float4 j4 = *(const float4*)(ajbuf + (size_t)n * 128 + lane * 4);
        float4 b4 = *(const float4*)(b1 + lane * 4);
        float r[4] = {
            deg * (a4.x + b4.x) + j4.x + acc.x,
            deg * (a4.y + b4.y) + j4.y + acc.y,
            deg * (a4.z + b4.z) + j4.z + acc.z,
            deg * (a4.w + b4.w) + j4.w + acc.w };
        #pragma unroll
        for (int q = 0; q < 4; ++q) {
            const float* wr = W1 + (4 * lane + q) * 9 + 6;   // We row
            r[q] += wr[0] * ex + wr[1] * ey + wr[2] * ez;
            r[q] = fmaxf(r[q], 0.f);
        }
        *(float4*)(h + (size_t)n * 128 + lane * 4) = make_float4(r[0], r[1], r[2], r[3]);
        if (lane == 0) {
            eagg[n * 3 + 0] = ex;
            eagg[n * 3 + 1] = ey;
            eagg[n * 3 + 2] = ez;
        }
    }
}

// ---- gather with fused epilogue (layer 2): P=[ai|aj] ----------------------

template <int FOUT, bool RELU>
__global__ __launch_bounds__(256) void gather_epi(
    const float* __restrict__ P, const float* __restrict__ W,
    const float* __restrict__ bvec, const float* __restrict__ eagg,
    const int* __restrict__ rowstart, const int2* __restrict__ csr,
    float* __restrict__ h, int n_nodes, int WROW)
{
    constexpr int NC = 2 * FOUT;
    int wave = threadIdx.x >> 6, lane = threadIdx.x & 63;
    int n = blockIdx.x * 4 + wave;
    if (n >= n_nodes) return;

    int s0 = rowstart[n], s1 = rowstart[n + 1];
    const float* Pr = P + (size_t)n * NC;
    float ai = Pr[lane];
    float aj = Pr[FOUT + lane];
    int wo = lane * WROW + (WROW - 3);
    float we = W[wo] * eagg[n * 3] + W[wo + 1] * eagg[n * 3 + 1] + W[wo + 2] * eagg[n * 3 + 2];
    float deg = (float)(s1 - s0 + 1);
    float acc = deg * (ai + bvec[lane]) + aj + we;

    for (int i = s0; i < s1; ++i) {
        int s = csr[i].x;
        acc += P[(size_t)s * NC + FOUT + lane];
    }
    if (RELU) acc = fmaxf(acc, 0.f);
    h[(size_t)n * FOUT + lane] = acc;
}

// ---- final: gather(32)+epilogue + classifier + log_softmax ----------------

__global__ __launch_bounds__(256) void gather_final_epi(
    const float* __restrict__ P, const float* __restrict__ W,
    const float* __restrict__ bvec, const float* __restrict__ eagg,
    const int* __restrict__ rowstart, const int2* __restrict__ csr,
    const float* __restrict__ Wc, const float* __restrict__ bc,
    float* __restrict__ out, int n_nodes, int WROW)
{
    int wave = threadIdx.x >> 6, lane = threadIdx.x & 63;
    int n = blockIdx.x * 4 + wave;
    if (n >= n_nodes) return;

    int s0 = rowstart[n], s1 = rowstart[n + 1];
    float acc = 0.f;
    if (lane < 32) {
        const float* Pr = P + (size_t)n * 64;
        float ai = Pr[lane];
        float aj = Pr[32 + lane];
        int wo = lane * WROW + (WROW - 3);
        float we = W[wo] * eagg[n * 3] + W[wo + 1] * eagg[n * 3 + 1] + W[wo + 2] * eagg[n * 3 + 2];
        float deg = (float)(s1 - s0 + 1);
        acc = deg * (ai + bvec[lane]) + aj + we;
    }
    for (int i = s0; i < s1; ++i) {
        int s = csr[i].x;
        if (lane < 32) acc += P[(size_t)s * 64 + 32 + lane];
    }
    float logits[4];
    #pragma unroll
    for (int j = 0; j < 4; ++j) {
        float v = (lane < 32) ? acc * Wc[j * 32 + lane] : 0.f;
        v += __shfl_down(v, 32);
        v += __shfl_down(v, 16);
        v += __shfl_down(v, 8);
        v += __shfl_down(v, 4);
        v += __shfl_down(v, 2);
        v += __shfl_down(v, 1);
        logits[j] = v;
    }
    if (lane == 0) {
        float l0 = logits[0] + bc[0], l1 = logits[1] + bc[1];
        float l2 = logits[2] + bc[2], l3 = logits[3] + bc[3];
        float m = fmaxf(fmaxf(l0, l1), fmaxf(l2, l3));
        float lse = logf(expf(l0 - m) + expf(l1 - m) + expf(l2 - m) + expf(l3 - m));
        float4 o = make_float4(l0 - m - lse, l1 - m - lse, l2 - m - lse, l3 - m - lse);
        *(float4*)(out + n * 4) = o;
    }
}

// ---------------------------------------------------------------------------

extern "C" void kernel_launch(void* const* d_in, const int* in_sizes, int n_in,
                              void* d_out, int out_size, void* d_ws, size_t ws_size,
                              hipStream_t stream)
{
    const float* x    = (const float*)d_in[0];
    const int*   ei   = (const int*)  d_in[1];
    const float* ea   = (const float*)d_in[2];
    const float* W1   = (const float*)d_in[3];
    const float* b1   = (const float*)d_in[4];
    const float* W2   = (const float*)d_in[5];
    const float* b2   = (const float*)d_in[6];
    const float* W3   = (const float*)d_in[7];
    const float* b3   = (const float*)d_in[8];
    const float* Wc   = (const float*)d_in[9];
    const float* bc   = (const float*)d_in[10];
    float* out = (float*)d_out;

    const int N = in_sizes[0] / 3;
    const int E = in_sizes[1] / 2;

    char* ws = (char*)d_ws;
    size_t off = 0;
    int*   count    = (int*)(ws + off);   off = align256(off + (size_t)N * 4);
    float* eagg     = (float*)(ws + off); off = align256(off + (size_t)N * 12);
    int*   pos      = (int*)(ws + off);   off = align256(off + (size_t)E * 4);
    int*   rowstart = (int*)(ws + off);   off = align256(off + (size_t)(N + 1) * 4);
    int2*  csr      = (int2*)(ws + off);  off = align256(off + (size_t)E * 8);
    int*   bsum     = (int*)(ws + off);   off = align256(off + 256);
    int*   bexcl    = (int*)(ws + off);   off = align256(off + 256);
    float* bufA     = (float*)(ws + off); off = align256(off + (size_t)N * 128 * 4);
    float* bufB     = (float*)(ws + off); off = align256(off + (size_t)N * 128 * 4);
    float* bufC     = (float*)(ws + off); off = align256(off + (size_t)N * 128 * 4);
    (void)ws_size;

    hipMemsetAsync(count, 0, (size_t)N * 4, stream);

    const int eb = (E + 255) / 256;
    build_count<<<eb, 256, 0, stream>>>(ei, count, pos, E);

    const int nb1 = (N + 1023) / 1024;
    scan_pass1<<<nb1, 256, 0, stream>>>(count, rowstart, bsum, N);
    scan_pass2<<<1, 64, 0, stream>>>(bsum, bexcl, nb1);
    scan_pass3<<<(N + 1 + 255) / 256, 256, 0, stream>>>(rowstart, bexcl, N);
    csr_scatter<<<eb, 256, 0, stream>>>(ei, pos, rowstart, csr, E);

    const int mt = (N + 63) / 64;

    // layer 1: 3 -> 128, relu (ai=bufA, aj=bufB, h1=bufC); eagg computed here
    node_linear<3, 128><<<(N + 1) / 2, 256, 0, stream>>>(x, W1, bufA, bufB, N);
    gather1<<<(N + 3) / 4, 256, 0, stream>>>(bufA, bufB, rowstart, csr, ea, W1, b1, eagg, bufC, N);

    // layer 2: 128 -> 64, relu  (P2 = bufA [N x 128], h2 = bufB [N x 64])
    gemm_tile<128, 64, 64><<<dim3(mt, 2), 256, 0, stream>>>(bufC, W2, bufA, N);
    gather_epi<64, true><<<(N + 3) / 4, 256, 0, stream>>>(bufA, W2, b2, eagg, rowstart, csr, bufB, N, 259);

    // layer 3: 64 -> 32  (P3 = bufA [N x 64]); fused classifier + log_softmax
    gemm_tile<64, 64, 32><<<dim3(mt, 1), 256, 0, stream>>>(bufB, W3, bufA, N);
    gather_final_epi<<<(N + 3) / 4, 256, 0, stream>>>(bufA, W3, b3, eagg, rowstart, csr, Wc, bc, out, N, 131);
}

// Round 4
// 339.131 us; speedup vs baseline: 2.4341x; 1.3667x over previous
//
#include <hip/hip_runtime.h>
#include <math.h>

// ---------------------------------------------------------------------------
// GCN (EdgeConv x3 + classifier + log_softmax) on MI355X.
// R4: layer3+classifier collapsed algebraically (everything after relu(h2)
// is linear): logits = deg*(U+db) + Z_self + sum_e Z[src] + eagg@C^T + bc,
// with U=h2@(Wc*Wi3)^T, Z=h2@(Wc*Wj3)^T computed INSIDE the layer-2 gather
// epilogue (h2 never materialized). Final gather reads 16 B/edge from an
// 800 KB L2-resident Z. Gathers use multi-edge float4 loads, all 64 lanes.
// ---------------------------------------------------------------------------

static inline size_t align256(size_t x) { return (x + 255) & ~size_t(255); }

// ---- CSR build ------------------------------------------------------------

__global__ __launch_bounds__(256) void build_count(
    const int* __restrict__ ei, int* __restrict__ count,
    int* __restrict__ pos, int E)
{
    int e = blockIdx.x * 256 + threadIdx.x;
    if (e >= E) return;
    pos[e] = atomicAdd(&count[ei[E + e]], 1);
}

__global__ __launch_bounds__(256) void scan_pass1(
    const int* __restrict__ count, int* __restrict__ rowstart,
    int* __restrict__ bsum, int n)
{
    __shared__ int sh[256];
    const int tid = threadIdx.x;
    const int base = blockIdx.x * 1024 + tid * 4;
    int v0 = 0, v1 = 0, v2 = 0, v3 = 0;
    if (base + 3 < n) {
        int4 c = *(const int4*)(count + base);
        v0 = c.x; v1 = c.y; v2 = c.z; v3 = c.w;
    } else {
        if (base + 0 < n) v0 = count[base + 0];
        if (base + 1 < n) v1 = count[base + 1];
        if (base + 2 < n) v2 = count[base + 2];
        if (base + 3 < n) v3 = count[base + 3];
    }
    int tsum = v0 + v1 + v2 + v3;
    sh[tid] = tsum;
    __syncthreads();
    for (int off = 1; off < 256; off <<= 1) {
        int t = (tid >= off) ? sh[tid - off] : 0;
        __syncthreads();
        sh[tid] += t;
        __syncthreads();
    }
    int excl = sh[tid] - tsum;
    int p0 = excl + v0, p1 = p0 + v1, p2 = p1 + v2, p3 = p2 + v3;
    if (base + 0 < n) rowstart[base + 1] = p0;
    if (base + 1 < n) rowstart[base + 2] = p1;
    if (base + 2 < n) rowstart[base + 3] = p2;
    if (base + 3 < n) rowstart[base + 4] = p3;
    if (tid == 255) bsum[blockIdx.x] = sh[255];
}

__global__ __launch_bounds__(64) void scan_pass2(
    const int* __restrict__ bsum, int* __restrict__ bexcl, int nb)
{
    int lane = threadIdx.x;
    int own = (lane < nb) ? bsum[lane] : 0;
    int x = own;
    for (int off = 1; off < 64; off <<= 1) {
        int t = __shfl_up(x, off);
        if (lane >= off) x += t;
    }
    bexcl[lane] = x - own;
}

__global__ __launch_bounds__(256) void scan_pass3(
    int* __restrict__ rowstart, const int* __restrict__ bexcl, int n)
{
    int j = blockIdx.x * 256 + threadIdx.x;
    if (j > n) return;
    if (j == 0) { rowstart[0] = 0; return; }
    int b = (j - 1) >> 10;
    if (b > 0) rowstart[j] += bexcl[b];
}

__global__ __launch_bounds__(256) void csr_scatter(
    const int* __restrict__ ei, const int* __restrict__ pos,
    const int* __restrict__ rowstart, int2* __restrict__ csr, int E)
{
    int e = blockIdx.x * 256 + threadIdx.x;
    if (e >= E) return;
    int d = ei[E + e];
    csr[rowstart[d] + pos[e]] = make_int2(ei[e], e);   // (src, edge id)
}

// ---- precompute collapsed layer-3 matrices --------------------------------
// AB[8][64]: rows 0-3 = Wc@Wi3, rows 4-7 = Wc@Wj3.
// consts[20]: [0..3]=b3@Wc^T, [4..7]=bc, [8..19]=Wc@We3 (4x3 row-major).

__global__ __launch_bounds__(256) void prep_collapse(
    const float* __restrict__ W3, const float* __restrict__ b3,
    const float* __restrict__ Wc, const float* __restrict__ bc,
    float* __restrict__ AB, float* __restrict__ consts)
{
    int t = threadIdx.x;
    for (int idx = t; idx < 512; idx += 256) {
        int j = idx >> 6, k = idx & 63;
        int jj = j & 3;
        int base = (j >= 4) ? 64 : 0;
        float s = 0.f;
        #pragma unroll
        for (int c = 0; c < 32; ++c)
            s += Wc[jj * 32 + c] * W3[c * 131 + base + k];
        AB[idx] = s;
    }
    if (t < 4) {
        float db = 0.f;
        for (int c = 0; c < 32; ++c) db += Wc[t * 32 + c] * b3[c];
        consts[t] = db;
        consts[4 + t] = bc[t];
        for (int q = 0; q < 3; ++q) {
            float s = 0.f;
            for (int c = 0; c < 32; ++c) s += Wc[t * 32 + c] * W3[c * 131 + 128 + q];
            consts[8 + t * 3 + q] = s;
        }
    }
}

// ---- layer-1 node linear (K=3) --------------------------------------------

template <int FIN, int FOUT>
__global__ __launch_bounds__(256) void node_linear(
    const float* __restrict__ x, const float* __restrict__ W,
    float* __restrict__ aibuf, float* __restrict__ ajbuf, int n_nodes)
{
    constexpr int WROW = 2 * FIN + 3;
    constexpr int PAD  = FOUT + 1;
    __shared__ float sWi[FIN * PAD];
    __shared__ float sWj[FIN * PAD];

    const int tid = threadIdx.x;
    constexpr int NPB = 256 / FOUT;
    const int c = tid % FOUT;
    const int n = blockIdx.x * NPB + tid / FOUT;

    for (int idx = tid; idx < FIN * FOUT; idx += 256) {
        int cc = idx / FIN, kk = idx % FIN;
        sWi[kk * PAD + cc] = W[cc * WROW + kk];
        sWj[kk * PAD + cc] = W[cc * WROW + FIN + kk];
    }
    __syncthreads();

    if (n >= n_nodes) return;
    float ai = 0.f, aj = 0.f;
    #pragma unroll
    for (int k = 0; k < FIN; ++k) {
        float xv = x[n * FIN + k];
        ai += xv * sWi[k * PAD + c];
        aj += xv * sWj[k * PAD + c];
    }
    aibuf[(size_t)n * FOUT + c] = ai;
    ajbuf[(size_t)n * FOUT + c] = aj;
}

// ---- register-blocked GEMM: P = x @ [Wi^T | Wj^T] -------------------------

template <int FIN, int NCB, int FOUT>
__global__ __launch_bounds__(256) void gemm_tile(
    const float* __restrict__ x, const float* __restrict__ W,
    float* __restrict__ P, int n_nodes)
{
    constexpr int NC = 2 * FOUT;
    constexpr int WROW = 2 * FIN + 3;
    __shared__ float sX[64 * FIN];
    __shared__ float sW[NCB * FIN];

    const int tid = threadIdx.x;
    const int tx = tid & 15;
    const int ty = tid >> 4;
    const int mbase = blockIdx.x * 64;
    const int jbase = blockIdx.y * NCB;

    constexpr int XT = 16 * FIN;
    for (int t = tid; t < XT; t += 256) {
        int r = t & 63, ch = t >> 6;
        int gn = mbase + r;
        float4 v = make_float4(0.f, 0.f, 0.f, 0.f);
        if (gn < n_nodes) v = *(const float4*)(x + (size_t)gn * FIN + ch * 4);
        *(float4*)(sX + (ch * 64 + r) * 4) = v;
    }
    for (int t = tid; t < NCB * FIN; t += 256) {
        int j = t / FIN, k = t % FIN;
        int jg = jbase + j;
        float w = (jg < FOUT) ? W[jg * WROW + k] : W[(jg - FOUT) * WROW + FIN + k];
        sW[((k >> 2) * NCB + j) * 4 + (k & 3)] = w;
    }
    __syncthreads();

    float acc[4][4];
    #pragma unroll
    for (int i = 0; i < 4; ++i)
        #pragma unroll
        for (int jj = 0; jj < 4; ++jj) acc[i][jj] = 0.f;

    #pragma unroll 2
    for (int k0 = 0; k0 < FIN; k0 += 4) {
        float4 a[4], bb[4];
        #pragma unroll
        for (int i = 0; i < 4; ++i)
            a[i] = *(const float4*)(sX + ((k0 >> 2) * 64 + (ty * 4 + i)) * 4);
        #pragma unroll
        for (int i = 0; i < 4; ++i)
            bb[i] = *(const float4*)(sW + ((k0 >> 2) * NCB + (tx + 16 * i)) * 4);
        #pragma unroll
        for (int mi = 0; mi < 4; ++mi)
            #pragma unroll
            for (int ji = 0; ji < 4; ++ji)
                acc[mi][ji] += a[mi].x * bb[ji].x + a[mi].y * bb[ji].y
                             + a[mi].z * bb[ji].z + a[mi].w * bb[ji].w;
    }

    #pragma unroll
    for (int mi = 0; mi < 4; ++mi) {
        int gn = mbase + ty * 4 + mi;
        if (gn >= n_nodes) continue;
        #pragma unroll
        for (int ji = 0; ji < 4; ++ji)
            P[(size_t)gn * NC + jbase + tx + 16 * ji] = acc[mi][ji];
    }
}

// ---- layer-1 gather: per-lane eagg loop + unrolled half-wave float4 -------

__global__ __launch_bounds__(256) void gather1(
    const float* __restrict__ aibuf, const float* __restrict__ ajbuf,
    const int* __restrict__ rowstart, const int2* __restrict__ csr,
    const float* __restrict__ ea, const float* __restrict__ W1,
    const float* __restrict__ b1, float* __restrict__ eagg,
    float* __restrict__ h, int n_nodes)
{
    int wave = threadIdx.x >> 6, lane = threadIdx.x & 63;
    int n = blockIdx.x * 4 + wave;
    if (n >= n_nodes) return;

    int s0 = rowstart[n], s1 = rowstart[n + 1];

    // eagg: one edge per lane
    float ex = 0.f, ey = 0.f, ez = 0.f;
    for (int i = s0 + lane; i < s1; i += 64) {
        int eid = csr[i].y;
        const float* ep = ea + (size_t)eid * 3;
        ex += ep[0]; ey += ep[1]; ez += ep[2];
    }
    #pragma unroll
    for (int off = 1; off < 64; off <<= 1) {
        ex += __shfl_xor(ex, off);
        ey += __shfl_xor(ey, off);
        ez += __shfl_xor(ez, off);
    }

    // aj rows: 2 edges per iter across half-waves, unrolled x2
    int half = lane >> 5;
    int l = lane & 31;
    float4 acc = make_float4(0.f, 0.f, 0.f, 0.f);
    int i = s0 + half;
    for (; i + 3 < s1; i += 4) {
        int sA = csr[i].x, sB = csr[i + 2].x;
        float4 vA = *(const float4*)(ajbuf + (size_t)sA * 128 + l * 4);
        float4 vB = *(const float4*)(ajbuf + (size_t)sB * 128 + l * 4);
        acc.x += vA.x + vB.x; acc.y += vA.y + vB.y;
        acc.z += vA.z + vB.z; acc.w += vA.w + vB.w;
    }
    for (; i < s1; i += 2) {
        int s = csr[i].x;
        float4 v = *(const float4*)(ajbuf + (size_t)s * 128 + l * 4);
        acc.x += v.x; acc.y += v.y; acc.z += v.z; acc.w += v.w;
    }
    acc.x += __shfl_xor(acc.x, 32);
    acc.y += __shfl_xor(acc.y, 32);
    acc.z += __shfl_xor(acc.z, 32);
    acc.w += __shfl_xor(acc.w, 32);

    if (lane < 32) {
        float deg = (float)(s1 - s0 + 1);
        float4 a4 = *(const float4*)(aibuf + (size_t)n * 128 + lane * 4);
        float4 j4 = *(const float4*)(ajbuf + (size_t)n * 128 + lane * 4);
        float4 b4 = *(const float4*)(b1 + lane * 4);
        float r[4] = {
            deg * (a4.x + b4.x) + j4.x + acc.x,
            deg * (a4.y + b4.y) + j4.y + acc.y,
            deg * (a4.z + b4.z) + j4.z + acc.z,
            deg * (a4.w + b4.w) + j4.w + acc.w };
        #pragma unroll
        for (int q = 0; q < 4; ++q) {
            const float* wr = W1 + (4 * lane + q) * 9 + 6;
            r[q] += wr[0] * ex + wr[1] * ey + wr[2] * ez;
            r[q] = fmaxf(r[q], 0.f);
        }
        *(float4*)(h + (size_t)n * 128 + lane * 4) = make_float4(r[0], r[1], r[2], r[3]);
        if (lane == 0) {
            eagg[n * 3 + 0] = ex;
            eagg[n * 3 + 1] = ey;
            eagg[n * 3 + 2] = ez;
        }
    }
}

// ---- layer-2 gather + relu + fused U/Z projection -------------------------
// 4 edges/iter (lane>>4 = edge-in-group, lane&15 = float4 chunk of 64-ch row),
// 8-edge unroll. h2 never hits memory: projected to U=h2@A^T, Z=h2@B^T.

__global__ __launch_bounds__(256) void gather_epi2(
    const float* __restrict__ P, const float* __restrict__ W2,
    const float* __restrict__ b2, const float* __restrict__ eagg,
    const int* __restrict__ rowstart, const int2* __restrict__ csr,
    const float* __restrict__ AB, float* __restrict__ U, float* __restrict__ Z,
    int n_nodes)
{
    constexpr int WROW = 259;
    __shared__ float sAB[8 * 64];
    const int tid = threadIdx.x;
    for (int t = tid; t < 512; t += 256) sAB[t] = AB[t];
    __syncthreads();

    int wave = tid >> 6, lane = tid & 63;
    int n = blockIdx.x * 4 + wave;
    if (n >= n_nodes) return;

    int s0 = rowstart[n], s1 = rowstart[n + 1];
    int eg = lane >> 4, ch = lane & 15;

    float4 acc = make_float4(0.f, 0.f, 0.f, 0.f);
    int i = s0;
    for (; i + 7 < s1; i += 8) {
        int sA = csr[i + eg].x, sB = csr[i + 4 + eg].x;
        float4 vA = *(const float4*)(P + (size_t)sA * 128 + 64 + ch * 4);
        float4 vB = *(const float4*)(P + (size_t)sB * 128 + 64 + ch * 4);
        acc.x += vA.x + vB.x; acc.y += vA.y + vB.y;
        acc.z += vA.z + vB.z; acc.w += vA.w + vB.w;
    }
    for (; i < s1; i += 4) {
        int e = i + eg;
        if (e < s1) {
            int s = csr[e].x;
            float4 v = *(const float4*)(P + (size_t)s * 128 + 64 + ch * 4);
            acc.x += v.x; acc.y += v.y; acc.z += v.z; acc.w += v.w;
        }
    }
    acc.x += __shfl_xor(acc.x, 16); acc.y += __shfl_xor(acc.y, 16);
    acc.z += __shfl_xor(acc.z, 16); acc.w += __shfl_xor(acc.w, 16);
    acc.x += __shfl_xor(acc.x, 32); acc.y += __shfl_xor(acc.y, 32);
    acc.z += __shfl_xor(acc.z, 32); acc.w += __shfl_xor(acc.w, 32);

    float pj[8];
    #pragma unroll
    for (int j = 0; j < 8; ++j) pj[j] = 0.f;

    if (lane < 16) {
        float deg = (float)(s1 - s0 + 1);
        float4 ai4 = *(const float4*)(P + (size_t)n * 128 + ch * 4);
        float4 aj4 = *(const float4*)(P + (size_t)n * 128 + 64 + ch * 4);
        float4 b4  = *(const float4*)(b2 + ch * 4);
        float e0 = eagg[n * 3], e1 = eagg[n * 3 + 1], e2 = eagg[n * 3 + 2];
        float r[4];
        float av[4] = {ai4.x, ai4.y, ai4.z, ai4.w};
        float jv[4] = {aj4.x, aj4.y, aj4.z, aj4.w};
        float bv[4] = {b4.x, b4.y, b4.z, b4.w};
        float cv[4] = {acc.x, acc.y, acc.z, acc.w};
        #pragma unroll
        for (int q = 0; q < 4; ++q) {
            int c = ch * 4 + q;
            const float* wr = W2 + c * WROW + (WROW - 3);
            float we = wr[0] * e0 + wr[1] * e1 + wr[2] * e2;
            r[q] = fmaxf(deg * (av[q] + bv[q]) + jv[q] + we + cv[q], 0.f);
        }
        #pragma unroll
        for (int j = 0; j < 8; ++j) {
            float4 w4 = *(const float4*)(sAB + j * 64 + ch * 4);
            pj[j] = r[0] * w4.x + r[1] * w4.y + r[2] * w4.z + r[3] * w4.w;
        }
    }
    #pragma unroll
    for (int off = 1; off < 16; off <<= 1)
        #pragma unroll
        for (int j = 0; j < 8; ++j) pj[j] += __shfl_xor(pj[j], off);

    if (lane == 0) {
        *(float4*)(U + (size_t)n * 4) = make_float4(pj[0], pj[1], pj[2], pj[3]);
        *(float4*)(Z + (size_t)n * 4) = make_float4(pj[4], pj[5], pj[6], pj[7]);
    }
}

// ---- final: thread per node, sum Z[src] + log_softmax ---------------------

__global__ __launch_bounds__(256) void final_softmax(
    const float* __restrict__ U, const float* __restrict__ Z,
    const float* __restrict__ eagg, const int* __restrict__ rowstart,
    const int2* __restrict__ csr, const float* __restrict__ consts,
    float* __restrict__ out, int n_nodes)
{
    int n = blockIdx.x * 256 + threadIdx.x;
    if (n >= n_nodes) return;

    int s0 = rowstart[n], s1 = rowstart[n + 1];
    float deg = (float)(s1 - s0 + 1);
    float4 u = *(const float4*)(U + (size_t)n * 4);
    float4 acc = *(const float4*)(Z + (size_t)n * 4);   // self-loop aj term
    float e0 = eagg[n * 3], e1 = eagg[n * 3 + 1], e2 = eagg[n * 3 + 2];

    int i = s0;
    for (; i + 1 < s1; i += 2) {
        int sA = csr[i].x, sB = csr[i + 1].x;
        float4 zA = *(const float4*)(Z + (size_t)sA * 4);
        float4 zB = *(const float4*)(Z + (size_t)sB * 4);
        acc.x += zA.x + zB.x; acc.y += zA.y + zB.y;
        acc.z += zA.z + zB.z; acc.w += zA.w + zB.w;
    }
    if (i < s1) {
        float4 z = *(const float4*)(Z + (size_t)csr[i].x * 4);
        acc.x += z.x; acc.y += z.y; acc.z += z.z; acc.w += z.w;
    }

    float lg[4];
    float uv[4] = {u.x, u.y, u.z, u.w};
    float av[4] = {acc.x, acc.y, acc.z, acc.w};
    #pragma unroll
    for (int j = 0; j < 4; ++j) {
        lg[j] = deg * (uv[j] + consts[j]) + av[j] + consts[4 + j]
              + consts[8 + j * 3] * e0 + consts[9 + j * 3] * e1 + consts[10 + j * 3] * e2;
    }
    float m = fmaxf(fmaxf(lg[0], lg[1]), fmaxf(lg[2], lg[3]));
    float lse = logf(expf(lg[0] - m) + expf(lg[1] - m) + expf(lg[2] - m) + expf(lg[3] - m));
    *(float4*)(out + (size_t)n * 4) =
        make_float4(lg[0] - m - lse, lg[1] - m - lse, lg[2] - m - lse, lg[3] - m - lse);
}

// ---------------------------------------------------------------------------

extern "C" void kernel_launch(void* const* d_in, const int* in_sizes, int n_in,
                              void* d_out, int out_size, void* d_ws, size_t ws_size,
                              hipStream_t stream)
{
    const float* x    = (const float*)d_in[0];
    const int*   ei   = (const int*)  d_in[1];
    const float* ea   = (const float*)d_in[2];
    const float* W1   = (const float*)d_in[3];
    const float* b1   = (const float*)d_in[4];
    const float* W2   = (const float*)d_in[5];
    const float* b2   = (const float*)d_in[6];
    const float* W3   = (const float*)d_in[7];
    const float* b3   = (const float*)d_in[8];
    const float* Wc   = (const float*)d_in[9];
    const float* bc   = (const float*)d_in[10];
    float* out = (float*)d_out;

    const int N = in_sizes[0] / 3;
    const int E = in_sizes[1] / 2;

    char* ws = (char*)d_ws;
    size_t off = 0;
    int*   count    = (int*)(ws + off);   off = align256(off + (size_t)N * 4);
    float* eagg     = (float*)(ws + off); off = align256(off + (size_t)N * 12);
    int*   pos      = (int*)(ws + off);   off = align256(off + (size_t)E * 4);
    int*   rowstart = (int*)(ws + off);   off = align256(off + (size_t)(N + 1) * 4);
    int2*  csr      = (int2*)(ws + off);  off = align256(off + (size_t)E * 8);
    int*   bsum     = (int*)(ws + off);   off = align256(off + 256);
    int*   bexcl    = (int*)(ws + off);   off = align256(off + 256);
    float* AB       = (float*)(ws + off); off = align256(off + 512 * 4);
    float* consts   = (float*)(ws + off); off = align256(off + 32 * 4);
    float* Ubuf     = (float*)(ws + off); off = align256(off + (size_t)N * 16);
    float* Zbuf     = (float*)(ws + off); off = align256(off + (size_t)N * 16);
    float* bufA     = (float*)(ws + off); off = align256(off + (size_t)N * 128 * 4);
    float* bufB     = (float*)(ws + off); off = align256(off + (size_t)N * 128 * 4);
    float* bufC     = (float*)(ws + off); off = align256(off + (size_t)N * 128 * 4);
    (void)ws_size;

    hipMemsetAsync(count, 0, (size_t)N * 4, stream);

    const int eb = (E + 255) / 256;
    build_count<<<eb, 256, 0, stream>>>(ei, count, pos, E);

    const int nb1 = (N + 1023) / 1024;
    scan_pass1<<<nb1, 256, 0, stream>>>(count, rowstart, bsum, N);
    scan_pass2<<<1, 64, 0, stream>>>(bsum, bexcl, nb1);
    scan_pass3<<<(N + 1 + 255) / 256, 256, 0, stream>>>(rowstart, bexcl, N);
    csr_scatter<<<eb, 256, 0, stream>>>(ei, pos, rowstart, csr, E);

    prep_collapse<<<1, 256, 0, stream>>>(W3, b3, Wc, bc, AB, consts);

    const int mt = (N + 63) / 64;

    // layer 1: 3 -> 128, relu (ai=bufA, aj=bufB, h1=bufC); eagg computed here
    node_linear<3, 128><<<(N + 1) / 2, 256, 0, stream>>>(x, W1, bufA, bufB, N);
    gather1<<<(N + 3) / 4, 256, 0, stream>>>(bufA, bufB, rowstart, csr, ea, W1, b1, eagg, bufC, N);

    // layer 2: 128 -> 64  (P2 = bufA [N x 128]); gather+relu+project -> U,Z
    gemm_tile<128, 64, 64><<<dim3(mt, 2), 256, 0, stream>>>(bufC, W2, bufA, N);
    gather_epi2<<<(N + 3) / 4, 256, 0, stream>>>(bufA, W2, b2, eagg, rowstart, csr, AB, Ubuf, Zbuf, N);

    // collapsed layer 3 + classifier + log_softmax
    final_softmax<<<(N + 255) / 256, 256, 0, stream>>>(Ubuf, Zbuf, eagg, rowstart, csr, consts, out, N);
}

// Round 5
// 310.608 us; speedup vs baseline: 2.6576x; 1.0918x over previous
//
#include <hip/hip_runtime.h>
#include <math.h>

// ---------------------------------------------------------------------------
// GCN (EdgeConv x3 + classifier + log_softmax) on MI355X.
// R5: layer-1 aggregation moved BEFORE the linear map (linearity in x):
//   xagg[n] = sum_e x[src], eagg[n] = sum_e ea  (12B/16B per edge, L2-resident)
//   h1 = relu([deg*x, x+xagg, eagg, deg] @ [Wi1|Wj1|We1|b1]^T)   (node-local)
// Layer 2: aj2 stored bf16 (6.4 MB, 128 B/row = 1 cache line), gathered with
// 8 edges/wave dwordx4 loads; epilogue projects h2 -> (U,Z) as in R4.
// Layer 3 + classifier stay collapsed into final_softmax over Z.
// ---------------------------------------------------------------------------

static inline size_t align256(size_t x) { return (x + 255) & ~size_t(255); }

__device__ inline unsigned short f2bf(float f) {
    unsigned u = __float_as_uint(f);
    unsigned r = (u + 0x7fffu + ((u >> 16) & 1u)) >> 16;
    return (unsigned short)r;
}
__device__ inline float bflo(unsigned u) { return __uint_as_float(u << 16); }
__device__ inline float bfhi(unsigned u) { return __uint_as_float(u & 0xffff0000u); }

// ---- CSR build ------------------------------------------------------------

__global__ __launch_bounds__(256) void build_count(
    const int* __restrict__ ei, int* __restrict__ count,
    int* __restrict__ pos, int E)
{
    int e = blockIdx.x * 256 + threadIdx.x;
    if (e >= E) return;
    pos[e] = atomicAdd(&count[ei[E + e]], 1);
}

__global__ __launch_bounds__(256) void scan_pass1(
    const int* __restrict__ count, int* __restrict__ rowstart,
    int* __restrict__ bsum, int n)
{
    __shared__ int sh[256];
    const int tid = threadIdx.x;
    const int base = blockIdx.x * 1024 + tid * 4;
    int v0 = 0, v1 = 0, v2 = 0, v3 = 0;
    if (base + 3 < n) {
        int4 c = *(const int4*)(count + base);
        v0 = c.x; v1 = c.y; v2 = c.z; v3 = c.w;
    } else {
        if (base + 0 < n) v0 = count[base + 0];
        if (base + 1 < n) v1 = count[base + 1];
        if (base + 2 < n) v2 = count[base + 2];
        if (base + 3 < n) v3 = count[base + 3];
    }
    int tsum = v0 + v1 + v2 + v3;
    sh[tid] = tsum;
    __syncthreads();
    for (int off = 1; off < 256; off <<= 1) {
        int t = (tid >= off) ? sh[tid - off] : 0;
        __syncthreads();
        sh[tid] += t;
        __syncthreads();
    }
    int excl = sh[tid] - tsum;
    int p0 = excl + v0, p1 = p0 + v1, p2 = p1 + v2, p3 = p2 + v3;
    if (base + 0 < n) rowstart[base + 1] = p0;
    if (base + 1 < n) rowstart[base + 2] = p1;
    if (base + 2 < n) rowstart[base + 3] = p2;
    if (base + 3 < n) rowstart[base + 4] = p3;
    if (tid == 255) bsum[blockIdx.x] = sh[255];
}

__global__ __launch_bounds__(64) void scan_pass2(
    const int* __restrict__ bsum, int* __restrict__ bexcl, int nb)
{
    int lane = threadIdx.x;
    int own = (lane < nb) ? bsum[lane] : 0;
    int x = own;
    for (int off = 1; off < 64; off <<= 1) {
        int t = __shfl_up(x, off);
        if (lane >= off) x += t;
    }
    bexcl[lane] = x - own;
}

__global__ __launch_bounds__(256) void scan_pass3(
    int* __restrict__ rowstart, const int* __restrict__ bexcl, int n)
{
    int j = blockIdx.x * 256 + threadIdx.x;
    if (j > n) return;
    if (j == 0) { rowstart[0] = 0; return; }
    int b = (j - 1) >> 10;
    if (b > 0) rowstart[j] += bexcl[b];
}

// scatter: csr_src (4 B) + permuted edge_attr as float4 (16 B, sequential-read later)
__global__ __launch_bounds__(256) void csr_scatter(
    const int* __restrict__ ei, const float* __restrict__ ea,
    const int* __restrict__ pos, const int* __restrict__ rowstart,
    int* __restrict__ csr_src, float4* __restrict__ eap, int E)
{
    int e = blockIdx.x * 256 + threadIdx.x;
    if (e >= E) return;
    int d = ei[E + e];
    int slot = rowstart[d] + pos[e];
    csr_src[slot] = ei[e];
    eap[slot] = make_float4(ea[e * 3], ea[e * 3 + 1], ea[e * 3 + 2], 0.f);
}

// ---- precompute collapsed layer-3 matrices --------------------------------
// AB[8][64]: rows 0-3 = Wc@Wi3, rows 4-7 = Wc@Wj3.
// consts[20]: [0..3]=b3@Wc^T, [4..7]=bc, [8..19]=Wc@We3 (4x3 row-major).

__global__ __launch_bounds__(256) void prep_collapse(
    const float* __restrict__ W3, const float* __restrict__ b3,
    const float* __restrict__ Wc, const float* __restrict__ bc,
    float* __restrict__ AB, float* __restrict__ consts)
{
    int t = threadIdx.x;
    for (int idx = t; idx < 512; idx += 256) {
        int j = idx >> 6, k = idx & 63;
        int jj = j & 3;
        int base = (j >= 4) ? 64 : 0;
        float s = 0.f;
        #pragma unroll
        for (int c = 0; c < 32; ++c)
            s += Wc[jj * 32 + c] * W3[c * 131 + base + k];
        AB[idx] = s;
    }
    if (t < 4) {
        float db = 0.f;
        for (int c = 0; c < 32; ++c) db += Wc[t * 32 + c] * b3[c];
        consts[t] = db;
        consts[4 + t] = bc[t];
        for (int q = 0; q < 3; ++q) {
            float s = 0.f;
            for (int c = 0; c < 32; ++c) s += Wc[t * 32 + c] * W3[c * 131 + 128 + q];
            consts[8 + t * 3 + q] = s;
        }
    }
}

// ---- aggregate raw x and ea over in-edges (thread per node) ---------------

__global__ __launch_bounds__(256) void gather_xe(
    const float* __restrict__ x, const int* __restrict__ rowstart,
    const int* __restrict__ csr_src, const float4* __restrict__ eap,
    float4* __restrict__ xagg4, float4* __restrict__ eagg4, int n_nodes)
{
    int n = blockIdx.x * 256 + threadIdx.x;
    if (n >= n_nodes) return;
    int s0 = rowstart[n], s1 = rowstart[n + 1];
    float xx = 0.f, xy = 0.f, xz = 0.f, ex = 0.f, ey = 0.f, ez = 0.f;
    for (int i = s0; i < s1; ++i) {
        int s = csr_src[i];
        xx += x[s * 3 + 0];
        xy += x[s * 3 + 1];
        xz += x[s * 3 + 2];
        float4 e = eap[i];
        ex += e.x; ey += e.y; ez += e.z;
    }
    xagg4[n] = make_float4(xx, xy, xz, 0.f);
    eagg4[n] = make_float4(ex, ey, ez, 0.f);
}

// ---- layer 1, fully node-local: h1 = relu(v @ M^T), v in R^10 -------------

__global__ __launch_bounds__(256) void h1_kernel(
    const float* __restrict__ x, const float* __restrict__ W1,
    const float* __restrict__ b1, const float4* __restrict__ xagg4,
    const float4* __restrict__ eagg4, const int* __restrict__ rowstart,
    float* __restrict__ h1, int n_nodes)
{
    __shared__ float sM[10 * 128];
    int tid = threadIdx.x;
    for (int t = tid; t < 1280; t += 256) {
        int k = t >> 7, c = t & 127;
        sM[t] = (k < 9) ? W1[c * 9 + k] : b1[c];
    }
    __syncthreads();

    int c = tid & 127;
    int n = blockIdx.x * 2 + (tid >> 7);
    if (n >= n_nodes) return;

    float deg = (float)(rowstart[n + 1] - rowstart[n] + 1);
    float x0 = x[n * 3], x1 = x[n * 3 + 1], x2 = x[n * 3 + 2];
    float4 xa = xagg4[n];
    float4 e4 = eagg4[n];
    float v[10] = { deg * x0, deg * x1, deg * x2,
                    x0 + xa.x, x1 + xa.y, x2 + xa.z,
                    e4.x, e4.y, e4.z, deg };
    float h = 0.f;
    #pragma unroll
    for (int k = 0; k < 10; ++k) h += v[k] * sM[k * 128 + c];
    h1[(size_t)n * 128 + c] = fmaxf(h, 0.f);
}

// ---- register-blocked GEMM: cols 0-63 -> AI2 fp32, 64-127 -> AJ2 bf16 -----

template <int FIN, int NCB, int FOUT>
__global__ __launch_bounds__(256) void gemm_tile(
    const float* __restrict__ x, const float* __restrict__ W,
    float* __restrict__ AI2, unsigned short* __restrict__ AJ2, int n_nodes)
{
    constexpr int WROW = 2 * FIN + 3;
    __shared__ float sX[64 * FIN];
    __shared__ float sW[NCB * FIN];

    const int tid = threadIdx.x;
    const int tx = tid & 15;
    const int ty = tid >> 4;
    const int mbase = blockIdx.x * 64;
    const int jbase = blockIdx.y * NCB;

    constexpr int XT = 16 * FIN;
    for (int t = tid; t < XT; t += 256) {
        int r = t & 63, ch = t >> 6;
        int gn = mbase + r;
        float4 v = make_float4(0.f, 0.f, 0.f, 0.f);
        if (gn < n_nodes) v = *(const float4*)(x + (size_t)gn * FIN + ch * 4);
        *(float4*)(sX + (ch * 64 + r) * 4) = v;
    }
    for (int t = tid; t < NCB * FIN; t += 256) {
        int j = t / FIN, k = t % FIN;
        int jg = jbase + j;
        float w = (jg < FOUT) ? W[jg * WROW + k] : W[(jg - FOUT) * WROW + FIN + k];
        sW[((k >> 2) * NCB + j) * 4 + (k & 3)] = w;
    }
    __syncthreads();

    float acc[4][4];
    #pragma unroll
    for (int i = 0; i < 4; ++i)
        #pragma unroll
        for (int jj = 0; jj < 4; ++jj) acc[i][jj] = 0.f;

    #pragma unroll 2
    for (int k0 = 0; k0 < FIN; k0 += 4) {
        float4 a[4], bb[4];
        #pragma unroll
        for (int i = 0; i < 4; ++i)
            a[i] = *(const float4*)(sX + ((k0 >> 2) * 64 + (ty * 4 + i)) * 4);
        #pragma unroll
        for (int i = 0; i < 4; ++i)
            bb[i] = *(const float4*)(sW + ((k0 >> 2) * NCB + (tx + 16 * i)) * 4);
        #pragma unroll
        for (int mi = 0; mi < 4; ++mi)
            #pragma unroll
            for (int ji = 0; ji < 4; ++ji)
                acc[mi][ji] += a[mi].x * bb[ji].x + a[mi].y * bb[ji].y
                             + a[mi].z * bb[ji].z + a[mi].w * bb[ji].w;
    }

    if (blockIdx.y == 0) {
        #pragma unroll
        for (int mi = 0; mi < 4; ++mi) {
            int gn = mbase + ty * 4 + mi;
            if (gn >= n_nodes) continue;
            #pragma unroll
            for (int ji = 0; ji < 4; ++ji)
                AI2[(size_t)gn * 64 + tx + 16 * ji] = acc[mi][ji];
        }
    } else {
        #pragma unroll
        for (int mi = 0; mi < 4; ++mi) {
            int gn = mbase + ty * 4 + mi;
            if (gn >= n_nodes) continue;
            #pragma unroll
            for (int ji = 0; ji < 4; ++ji)
                AJ2[(size_t)gn * 64 + tx + 16 * ji] = f2bf(acc[mi][ji]);
        }
    }
}

// ---- layer-2 gather (bf16 rows, 8 edges/wave) + relu + U/Z projection -----

__global__ __launch_bounds__(256) void gather2(
    const float* __restrict__ AI2, const unsigned short* __restrict__ AJ2,
    const float* __restrict__ W2, const float* __restrict__ b2,
    const float4* __restrict__ eagg4, const int* __restrict__ rowstart,
    const int* __restrict__ csr_src, const float* __restrict__ AB,
    float* __restrict__ U, float* __restrict__ Z, int n_nodes)
{
    __shared__ float sAB[512];
    __shared__ float sWe[192];
    const int tid = threadIdx.x;
    for (int t = tid; t < 512; t += 256) sAB[t] = AB[t];
    for (int t = tid; t < 192; t += 256) {
        int c = t / 3, q = t % 3;
        sWe[t] = W2[c * 259 + 256 + q];
    }
    __syncthreads();

    int wave = tid >> 6, lane = tid & 63;
    int n = blockIdx.x * 4 + wave;
    if (n >= n_nodes) return;

    int s0 = rowstart[n], s1 = rowstart[n + 1];
    int sub = lane >> 3, ch8 = lane & 7;   // 8 edges x 8 channel-chunks

    float acc[8];
    #pragma unroll
    for (int q = 0; q < 8; ++q) acc[q] = 0.f;

    int i = s0;
    for (; i + 7 < s1; i += 8) {
        int s = csr_src[i + sub];
        uint4 u = *(const uint4*)(AJ2 + (size_t)s * 64 + ch8 * 8);
        acc[0] += bflo(u.x); acc[1] += bfhi(u.x);
        acc[2] += bflo(u.y); acc[3] += bfhi(u.y);
        acc[4] += bflo(u.z); acc[5] += bfhi(u.z);
        acc[6] += bflo(u.w); acc[7] += bfhi(u.w);
    }
    if (i + sub < s1) {
        int s = csr_src[i + sub];
        uint4 u = *(const uint4*)(AJ2 + (size_t)s * 64 + ch8 * 8);
        acc[0] += bflo(u.x); acc[1] += bfhi(u.x);
        acc[2] += bflo(u.y); acc[3] += bfhi(u.y);
        acc[4] += bflo(u.z); acc[5] += bfhi(u.z);
        acc[6] += bflo(u.w); acc[7] += bfhi(u.w);
    }
    #pragma unroll
    for (int off = 8; off < 64; off <<= 1)
        #pragma unroll
        for (int q = 0; q < 8; ++q) acc[q] += __shfl_xor(acc[q], off);

    float pj[8];
    #pragma unroll
    for (int j = 0; j < 8; ++j) pj[j] = 0.f;

    if (lane < 8) {                         // lane == ch8, sub == 0
        float deg = (float)(s1 - s0 + 1);
        float4 e4 = eagg4[n];
        const float* aip = AI2 + (size_t)n * 64 + lane * 8;
        float4 aiA = *(const float4*)(aip);
        float4 aiB = *(const float4*)(aip + 4);
        uint4 su = *(const uint4*)(AJ2 + (size_t)n * 64 + lane * 8);
        float ajs[8] = { bflo(su.x), bfhi(su.x), bflo(su.y), bfhi(su.y),
                         bflo(su.z), bfhi(su.z), bflo(su.w), bfhi(su.w) };
        float4 bA = *(const float4*)(b2 + lane * 8);
        float4 bB = *(const float4*)(b2 + lane * 8 + 4);
        float av[8] = { aiA.x, aiA.y, aiA.z, aiA.w, aiB.x, aiB.y, aiB.z, aiB.w };
        float bv[8] = { bA.x, bA.y, bA.z, bA.w, bB.x, bB.y, bB.z, bB.w };
        float r[8];
        #pragma unroll
        for (int q = 0; q < 8; ++q) {
            int c = lane * 8 + q;
            float we = sWe[c * 3] * e4.x + sWe[c * 3 + 1] * e4.y + sWe[c * 3 + 2] * e4.z;
            r[q] = fmaxf(deg * (av[q] + bv[q]) + ajs[q] + we + acc[q], 0.f);
        }
        #pragma unroll
        for (int j = 0; j < 8; ++j) {
            float s = 0.f;
            #pragma unroll
            for (int q = 0; q < 8; ++q) s += r[q] * sAB[j * 64 + lane * 8 + q];
            pj[j] = s;
        }
    }
    #pragma unroll
    for (int off = 1; off < 8; off <<= 1)
        #pragma unroll
        for (int j = 0; j < 8; ++j) pj[j] += __shfl_xor(pj[j], off);

    if (lane == 0) {
        *(float4*)(U + (size_t)n * 4) = make_float4(pj[0], pj[1], pj[2], pj[3]);
        *(float4*)(Z + (size_t)n * 4) = make_float4(pj[4], pj[5], pj[6], pj[7]);
    }
}

// ---- final: thread per node, sum Z[src] + log_softmax ---------------------

__global__ __launch_bounds__(256) void final_softmax(
    const float* __restrict__ U, const float* __restrict__ Z,
    const float4* __restrict__ eagg4, const int* __restrict__ rowstart,
    const int* __restrict__ csr_src, const float* __restrict__ consts,
    float* __restrict__ out, int n_nodes)
{
    int n = blockIdx.x * 256 + threadIdx.x;
    if (n >= n_nodes) return;

    int s0 = rowstart[n], s1 = rowstart[n + 1];
    float deg = (float)(s1 - s0 + 1);
    float4 u = *(const float4*)(U + (size_t)n * 4);
    float4 acc = *(const float4*)(Z + (size_t)n * 4);   // self-loop term
    float4 e4 = eagg4[n];

    int i = s0;
    for (; i + 1 < s1; i += 2) {
        int sA = csr_src[i], sB = csr_src[i + 1];
        float4 zA = *(const float4*)(Z + (size_t)sA * 4);
        float4 zB = *(const float4*)(Z + (size_t)sB * 4);
        acc.x += zA.x + zB.x; acc.y += zA.y + zB.y;
        acc.z += zA.z + zB.z; acc.w += zA.w + zB.w;
    }
    if (i < s1) {
        float4 z = *(const float4*)(Z + (size_t)csr_src[i] * 4);
        acc.x += z.x; acc.y += z.y; acc.z += z.z; acc.w += z.w;
    }

    float lg[4];
    float uv[4] = { u.x, u.y, u.z, u.w };
    float av[4] = { acc.x, acc.y, acc.z, acc.w };
    #pragma unroll
    for (int j = 0; j < 4; ++j) {
        lg[j] = deg * (uv[j] + consts[j]) + av[j] + consts[4 + j]
              + consts[8 + j * 3] * e4.x + consts[9 + j * 3] * e4.y
              + consts[10 + j * 3] * e4.z;
    }
    float m = fmaxf(fmaxf(lg[0], lg[1]), fmaxf(lg[2], lg[3]));
    float lse = logf(expf(lg[0] - m) + expf(lg[1] - m) + expf(lg[2] - m) + expf(lg[3] - m));
    *(float4*)(out + (size_t)n * 4) =
        make_float4(lg[0] - m - lse, lg[1] - m - lse, lg[2] - m - lse, lg[3] - m - lse);
}

// ---------------------------------------------------------------------------

extern "C" void kernel_launch(void* const* d_in, const int* in_sizes, int n_in,
                              void* d_out, int out_size, void* d_ws, size_t ws_size,
                              hipStream_t stream)
{
    const float* x    = (const float*)d_in[0];
    const int*   ei   = (const int*)  d_in[1];
    const float* ea   = (const float*)d_in[2];
    const float* W1   = (const float*)d_in[3];
    const float* b1   = (const float*)d_in[4];
    const float* W2   = (const float*)d_in[5];
    const float* b2   = (const float*)d_in[6];
    const float* W3   = (const float*)d_in[7];
    const float* b3   = (const float*)d_in[8];
    const float* Wc   = (const float*)d_in[9];
    const float* bc   = (const float*)d_in[10];
    float* out = (float*)d_out;

    const int N = in_sizes[0] / 3;
    const int E = in_sizes[1] / 2;

    char* ws = (char*)d_ws;
    size_t off = 0;
    int*    count    = (int*)(ws + off);            off = align256(off + (size_t)N * 4);
    int*    pos      = (int*)(ws + off);            off = align256(off + (size_t)E * 4);
    int*    rowstart = (int*)(ws + off);            off = align256(off + (size_t)(N + 1) * 4);
    int*    csr_src  = (int*)(ws + off);            off = align256(off + (size_t)E * 4);
    float4* eap      = (float4*)(ws + off);         off = align256(off + (size_t)E * 16);
    int*    bsum     = (int*)(ws + off);            off = align256(off + 256);
    int*    bexcl    = (int*)(ws + off);            off = align256(off + 256);
    float*  AB       = (float*)(ws + off);          off = align256(off + 512 * 4);
    float*  consts   = (float*)(ws + off);          off = align256(off + 32 * 4);
    float4* xagg4    = (float4*)(ws + off);         off = align256(off + (size_t)N * 16);
    float4* eagg4    = (float4*)(ws + off);         off = align256(off + (size_t)N * 16);
    float*  h1buf    = (float*)(ws + off);          off = align256(off + (size_t)N * 128 * 4);
    float*  AI2      = (float*)(ws + off);          off = align256(off + (size_t)N * 64 * 4);
    unsigned short* AJ2 = (unsigned short*)(ws + off); off = align256(off + (size_t)N * 64 * 2);
    float*  Ubuf     = (float*)(ws + off);          off = align256(off + (size_t)N * 16);
    float*  Zbuf     = (float*)(ws + off);          off = align256(off + (size_t)N * 16);
    (void)ws_size;

    hipMemsetAsync(count, 0, (size_t)N * 4, stream);

    const int eb = (E + 255) / 256;
    build_count<<<eb, 256, 0, stream>>>(ei, count, pos, E);

    const int nb1 = (N + 1023) / 1024;
    scan_pass1<<<nb1, 256, 0, stream>>>(count, rowstart, bsum, N);
    scan_pass2<<<1, 64, 0, stream>>>(bsum, bexcl, nb1);
    scan_pass3<<<(N + 1 + 255) / 256, 256, 0, stream>>>(rowstart, bexcl, N);
    csr_scatter<<<eb, 256, 0, stream>>>(ei, ea, pos, rowstart, csr_src, eap, E);

    prep_collapse<<<1, 256, 0, stream>>>(W3, b3, Wc, bc, AB, consts);

    // layer 1 (aggregate-then-linear, all node-local after gather_xe)
    gather_xe<<<(N + 255) / 256, 256, 0, stream>>>(x, rowstart, csr_src, eap, xagg4, eagg4, N);
    h1_kernel<<<(N + 1) / 2, 256, 0, stream>>>(x, W1, b1, xagg4, eagg4, rowstart, h1buf, N);

    // layer 2: GEMM -> AI2 (fp32) + AJ2 (bf16); gather+relu+project -> U,Z
    const int mt = (N + 63) / 64;
    gemm_tile<128, 64, 64><<<dim3(mt, 2), 256, 0, stream>>>(h1buf, W2, AI2, AJ2, N);
    gather2<<<(N + 3) / 4, 256, 0, stream>>>(AI2, AJ2, W2, b2, eagg4, rowstart, csr_src, AB, Ubuf, Zbuf, N);

    // collapsed layer 3 + classifier + log_softmax
    final_softmax<<<(N + 255) / 256, 256, 0, stream>>>(Ubuf, Zbuf, eagg4, rowstart, csr_src, consts, out, N);
}

// Round 6
// 285.952 us; speedup vs baseline: 2.8867x; 1.0862x over previous
//
#include <hip/hip_runtime.h>
#include <math.h>

// ---------------------------------------------------------------------------
// GCN (EdgeConv x3 + classifier + log_softmax) on MI355X.
// R6: packed CSR: one uint2/edge {bf16 ea0|ea1, bf16 ea2 | src<<16} (8 B
// scattered write). gather2 preloads indices (coalesced) + shfl-broadcast,
// 2 row-loads in flight. gather_xe+h1 fused wave-per-node (lane-per-edge).
// final_softmax wave-per-node. Layer3+classifier stay collapsed (R4),
// layer-1 aggregation stays pre-linear (R5).
// ---------------------------------------------------------------------------

static inline size_t align256(size_t x) { return (x + 255) & ~size_t(255); }

__device__ inline unsigned short f2bf(float f) {
    unsigned u = __float_as_uint(f);
    unsigned r = (u + 0x7fffu + ((u >> 16) & 1u)) >> 16;
    return (unsigned short)r;
}
__device__ inline float bflo(unsigned u) { return __uint_as_float(u << 16); }
__device__ inline float bfhi(unsigned u) { return __uint_as_float(u & 0xffff0000u); }

// ---- CSR build ------------------------------------------------------------

__global__ __launch_bounds__(256) void build_count(
    const int* __restrict__ ei, int* __restrict__ count,
    int* __restrict__ pos, int E)
{
    int e4 = (blockIdx.x * 256 + threadIdx.x) * 4;
    if (e4 >= E) return;
    if (e4 + 3 < E) {
        int4 d = *(const int4*)(ei + E + e4);
        int4 po;
        po.x = atomicAdd(&count[d.x], 1);
        po.y = atomicAdd(&count[d.y], 1);
        po.z = atomicAdd(&count[d.z], 1);
        po.w = atomicAdd(&count[d.w], 1);
        *(int4*)(pos + e4) = po;
    } else {
        for (int e = e4; e < E; ++e)
            pos[e] = atomicAdd(&count[ei[E + e]], 1);
    }
}

__global__ __launch_bounds__(256) void scan_pass1(
    const int* __restrict__ count, int* __restrict__ rowstart,
    int* __restrict__ bsum, int n)
{
    __shared__ int sh[256];
    const int tid = threadIdx.x;
    const int base = blockIdx.x * 1024 + tid * 4;
    int v0 = 0, v1 = 0, v2 = 0, v3 = 0;
    if (base + 3 < n) {
        int4 c = *(const int4*)(count + base);
        v0 = c.x; v1 = c.y; v2 = c.z; v3 = c.w;
    } else {
        if (base + 0 < n) v0 = count[base + 0];
        if (base + 1 < n) v1 = count[base + 1];
        if (base + 2 < n) v2 = count[base + 2];
        if (base + 3 < n) v3 = count[base + 3];
    }
    int tsum = v0 + v1 + v2 + v3;
    sh[tid] = tsum;
    __syncthreads();
    for (int off = 1; off < 256; off <<= 1) {
        int t = (tid >= off) ? sh[tid - off] : 0;
        __syncthreads();
        sh[tid] += t;
        __syncthreads();
    }
    int excl = sh[tid] - tsum;
    int p0 = excl + v0, p1 = p0 + v1, p2 = p1 + v2, p3 = p2 + v3;
    if (base + 0 < n) rowstart[base + 1] = p0;
    if (base + 1 < n) rowstart[base + 2] = p1;
    if (base + 2 < n) rowstart[base + 3] = p2;
    if (base + 3 < n) rowstart[base + 4] = p3;
    if (tid == 255) bsum[blockIdx.x] = sh[255];
}

__global__ __launch_bounds__(64) void scan_pass2(
    const int* __restrict__ bsum, int* __restrict__ bexcl, int nb)
{
    int lane = threadIdx.x;
    int own = (lane < nb) ? bsum[lane] : 0;
    int x = own;
    for (int off = 1; off < 64; off <<= 1) {
        int t = __shfl_up(x, off);
        if (lane >= off) x += t;
    }
    bexcl[lane] = x - own;
}

__global__ __launch_bounds__(256) void scan_pass3(
    int* __restrict__ rowstart, const int* __restrict__ bexcl, int n)
{
    int j = blockIdx.x * 256 + threadIdx.x;
    if (j > n) return;
    if (j == 0) { rowstart[0] = 0; return; }
    int b = (j - 1) >> 10;
    if (b > 0) rowstart[j] += bexcl[b];
}

// scatter packed edge record: {bf16 e0 | bf16 e1 << 16, bf16 e2 | src << 16}
__global__ __launch_bounds__(256) void csr_scatter(
    const int* __restrict__ ei, const float* __restrict__ ea,
    const int* __restrict__ pos, const int* __restrict__ rowstart,
    uint2* __restrict__ csrp, int E)
{
    int e4 = (blockIdx.x * 256 + threadIdx.x) * 4;
    if (e4 >= E) return;
    if (e4 + 3 < E) {
        int4 s = *(const int4*)(ei + e4);
        int4 d = *(const int4*)(ei + E + e4);
        int4 po = *(const int4*)(pos + e4);
        float4 a = *(const float4*)(ea + (size_t)e4 * 3);
        float4 b = *(const float4*)(ea + (size_t)e4 * 3 + 4);
        float4 c = *(const float4*)(ea + (size_t)e4 * 3 + 8);
        float ev[12] = { a.x, a.y, a.z, a.w, b.x, b.y, b.z, b.w, c.x, c.y, c.z, c.w };
        int sv[4] = { s.x, s.y, s.z, s.w };
        int dv[4] = { d.x, d.y, d.z, d.w };
        int pv[4] = { po.x, po.y, po.z, po.w };
        #pragma unroll
        for (int r = 0; r < 4; ++r) {
            uint2 p;
            p.x = (unsigned)f2bf(ev[r * 3 + 0]) | ((unsigned)f2bf(ev[r * 3 + 1]) << 16);
            p.y = (unsigned)f2bf(ev[r * 3 + 2]) | ((unsigned)sv[r] << 16);
            csrp[rowstart[dv[r]] + pv[r]] = p;
        }
    } else {
        for (int e = e4; e < E; ++e) {
            uint2 p;
            p.x = (unsigned)f2bf(ea[e * 3 + 0]) | ((unsigned)f2bf(ea[e * 3 + 1]) << 16);
            p.y = (unsigned)f2bf(ea[e * 3 + 2]) | ((unsigned)ei[e] << 16);
            csrp[rowstart[ei[E + e]] + pos[e]] = p;
        }
    }
}

// ---- precompute collapsed layer-3 matrices --------------------------------

__global__ __launch_bounds__(256) void prep_collapse(
    const float* __restrict__ W3, const float* __restrict__ b3,
    const float* __restrict__ Wc, const float* __restrict__ bc,
    float* __restrict__ AB, float* __restrict__ consts)
{
    int t = threadIdx.x;
    for (int idx = t; idx < 512; idx += 256) {
        int j = idx >> 6, k = idx & 63;
        int jj = j & 3;
        int base = (j >= 4) ? 64 : 0;
        float s = 0.f;
        #pragma unroll
        for (int c = 0; c < 32; ++c)
            s += Wc[jj * 32 + c] * W3[c * 131 + base + k];
        AB[idx] = s;
    }
    if (t < 4) {
        float db = 0.f;
        for (int c = 0; c < 32; ++c) db += Wc[t * 32 + c] * b3[c];
        consts[t] = db;
        consts[4 + t] = bc[t];
        for (int q = 0; q < 3; ++q) {
            float s = 0.f;
            for (int c = 0; c < 32; ++c) s += Wc[t * 32 + c] * W3[c * 131 + 128 + q];
            consts[8 + t * 3 + q] = s;
        }
    }
}

// ---- fused layer-1: wave-per-node edge aggregation + node-local matvec ----
// h1 = relu([deg*x, x+xagg, eagg, deg] @ [Wi1|Wj1|We1|b1]^T)

__global__ __launch_bounds__(256) void h1_fused(
    const float* __restrict__ x, const float* __restrict__ W1,
    const float* __restrict__ b1, const int* __restrict__ rowstart,
    const uint2* __restrict__ csrp, float4* __restrict__ eagg4,
    float* __restrict__ h1, int n_nodes)
{
    __shared__ float sM[10 * 128];
    const int tid = threadIdx.x;
    for (int t = tid; t < 1280; t += 256) {
        int k = t >> 7, c = t & 127;
        sM[t] = (k < 9) ? W1[c * 9 + k] : b1[c];
    }
    __syncthreads();

    int wave = tid >> 6, lane = tid & 63;
    int n = blockIdx.x * 4 + wave;
    if (n >= n_nodes) return;

    int s0 = rowstart[n], s1 = rowstart[n + 1];
    float xx = 0.f, xy = 0.f, xz = 0.f, ex = 0.f, ey = 0.f, ez = 0.f;
    for (int i = s0 + lane; i < s1; i += 64) {
        uint2 p = csrp[i];
        int s = (int)(p.y >> 16);
        ex += bflo(p.x); ey += bfhi(p.x); ez += bflo(p.y);
        const float* xp = x + (size_t)s * 3;
        xx += xp[0]; xy += xp[1]; xz += xp[2];
    }
    #pragma unroll
    for (int off = 1; off < 64; off <<= 1) {
        xx += __shfl_xor(xx, off); xy += __shfl_xor(xy, off); xz += __shfl_xor(xz, off);
        ex += __shfl_xor(ex, off); ey += __shfl_xor(ey, off); ez += __shfl_xor(ez, off);
    }

    float deg = (float)(s1 - s0 + 1);
    float x0 = x[n * 3], x1 = x[n * 3 + 1], x2 = x[n * 3 + 2];
    float v[10] = { deg * x0, deg * x1, deg * x2,
                    x0 + xx, x1 + xy, x2 + xz,
                    ex, ey, ez, deg };
    float h0 = 0.f, h64 = 0.f;
    #pragma unroll
    for (int k = 0; k < 10; ++k) {
        h0  += v[k] * sM[k * 128 + lane];
        h64 += v[k] * sM[k * 128 + 64 + lane];
    }
    h1[(size_t)n * 128 + lane]      = fmaxf(h0, 0.f);
    h1[(size_t)n * 128 + 64 + lane] = fmaxf(h64, 0.f);
    if (lane == 0) eagg4[n] = make_float4(ex, ey, ez, 0.f);
}

// ---- register-blocked GEMM: cols 0-63 -> AI2 fp32, 64-127 -> AJ2 bf16 -----

template <int FIN, int NCB, int FOUT>
__global__ __launch_bounds__(256) void gemm_tile(
    const float* __restrict__ x, const float* __restrict__ W,
    float* __restrict__ AI2, unsigned short* __restrict__ AJ2, int n_nodes)
{
    constexpr int WROW = 2 * FIN + 3;
    __shared__ float sX[64 * FIN];
    __shared__ float sW[NCB * FIN];

    const int tid = threadIdx.x;
    const int tx = tid & 15;
    const int ty = tid >> 4;
    const int mbase = blockIdx.x * 64;
    const int jbase = blockIdx.y * NCB;

    constexpr int XT = 16 * FIN;
    for (int t = tid; t < XT; t += 256) {
        int r = t & 63, ch = t >> 6;
        int gn = mbase + r;
        float4 v = make_float4(0.f, 0.f, 0.f, 0.f);
        if (gn < n_nodes) v = *(const float4*)(x + (size_t)gn * FIN + ch * 4);
        *(float4*)(sX + (ch * 64 + r) * 4) = v;
    }
    for (int t = tid; t < NCB * FIN; t += 256) {
        int j = t / FIN, k = t % FIN;
        int jg = jbase + j;
        float w = (jg < FOUT) ? W[jg * WROW + k] : W[(jg - FOUT) * WROW + FIN + k];
        sW[((k >> 2) * NCB + j) * 4 + (k & 3)] = w;
    }
    __syncthreads();

    float acc[4][4];
    #pragma unroll
    for (int i = 0; i < 4; ++i)
        #pragma unroll
        for (int jj = 0; jj < 4; ++jj) acc[i][jj] = 0.f;

    #pragma unroll 2
    for (int k0 = 0; k0 < FIN; k0 += 4) {
        float4 a[4], bb[4];
        #pragma unroll
        for (int i = 0; i < 4; ++i)
            a[i] = *(const float4*)(sX + ((k0 >> 2) * 64 + (ty * 4 + i)) * 4);
        #pragma unroll
        for (int i = 0; i < 4; ++i)
            bb[i] = *(const float4*)(sW + ((k0 >> 2) * NCB + (tx + 16 * i)) * 4);
        #pragma unroll
        for (int mi = 0; mi < 4; ++mi)
            #pragma unroll
            for (int ji = 0; ji < 4; ++ji)
                acc[mi][ji] += a[mi].x * bb[ji].x + a[mi].y * bb[ji].y
                             + a[mi].z * bb[ji].z + a[mi].w * bb[ji].w;
    }

    if (blockIdx.y == 0) {
        #pragma unroll
        for (int mi = 0; mi < 4; ++mi) {
            int gn = mbase + ty * 4 + mi;
            if (gn >= n_nodes) continue;
            #pragma unroll
            for (int ji = 0; ji < 4; ++ji)
                AI2[(size_t)gn * 64 + tx + 16 * ji] = acc[mi][ji];
        }
    } else {
        #pragma unroll
        for (int mi = 0; mi < 4; ++mi) {
            int gn = mbase + ty * 4 + mi;
            if (gn >= n_nodes) continue;
            #pragma unroll
            for (int ji = 0; ji < 4; ++ji)
                AJ2[(size_t)gn * 64 + tx + 16 * ji] = f2bf(acc[mi][ji]);
        }
    }
}

// ---- layer-2 gather: preloaded indices, 2 rows in flight, bf16 rows -------

__global__ __launch_bounds__(256) void gather2(
    const float* __restrict__ AI2, const unsigned short* __restrict__ AJ2,
    const float* __restrict__ W2, const float* __restrict__ b2,
    const float4* __restrict__ eagg4, const int* __restrict__ rowstart,
    const uint2* __restrict__ csrp, const float* __restrict__ AB,
    float* __restrict__ U, float* __restrict__ Z, int n_nodes)
{
    __shared__ float sAB[512];
    __shared__ float sWe[192];
    const int tid = threadIdx.x;
    for (int t = tid; t < 512; t += 256) sAB[t] = AB[t];
    for (int t = tid; t < 192; t += 256) {
        int c = t / 3, q = t % 3;
        sWe[t] = W2[c * 259 + 256 + q];
    }
    __syncthreads();

    int wave = tid >> 6, lane = tid & 63;
    int n = blockIdx.x * 4 + wave;
    if (n >= n_nodes) return;

    int s0 = rowstart[n], s1 = rowstart[n + 1];
    int sub = lane >> 3, ch8 = lane & 7;

    float acc[8];
    #pragma unroll
    for (int q = 0; q < 8; ++q) acc[q] = 0.f;

    for (int base = s0; base < s1; base += 64) {
        int rem = s1 - base; if (rem > 64) rem = 64;
        int myidx = 0;
        if (lane < rem) myidx = (int)(csrp[base + lane].y >> 16);
        int fg = rem >> 3;
        int g = 0;
        for (; g + 2 <= fg; g += 2) {
            int sA = __shfl(myidx, g * 8 + sub);
            int sB = __shfl(myidx, g * 8 + 8 + sub);
            uint4 uA = *(const uint4*)(AJ2 + (size_t)sA * 64 + ch8 * 8);
            uint4 uB = *(const uint4*)(AJ2 + (size_t)sB * 64 + ch8 * 8);
            acc[0] += bflo(uA.x) + bflo(uB.x); acc[1] += bfhi(uA.x) + bfhi(uB.x);
            acc[2] += bflo(uA.y) + bflo(uB.y); acc[3] += bfhi(uA.y) + bfhi(uB.y);
            acc[4] += bflo(uA.z) + bflo(uB.z); acc[5] += bfhi(uA.z) + bfhi(uB.z);
            acc[6] += bflo(uA.w) + bflo(uB.w); acc[7] += bfhi(uA.w) + bfhi(uB.w);
        }
        if (g < fg) {
            int sA = __shfl(myidx, g * 8 + sub);
            uint4 u = *(const uint4*)(AJ2 + (size_t)sA * 64 + ch8 * 8);
            acc[0] += bflo(u.x); acc[1] += bfhi(u.x);
            acc[2] += bflo(u.y); acc[3] += bfhi(u.y);
            acc[4] += bflo(u.z); acc[5] += bfhi(u.z);
            acc[6] += bflo(u.w); acc[7] += bfhi(u.w);
        }
        int tail = rem & 7;
        if (tail) {
            int s = __shfl(myidx, fg * 8 + sub);
            if (sub < tail) {
                uint4 u = *(const uint4*)(AJ2 + (size_t)s * 64 + ch8 * 8);
                acc[0] += bflo(u.x); acc[1] += bfhi(u.x);
                acc[2] += bflo(u.y); acc[3] += bfhi(u.y);
                acc[4] += bflo(u.z); acc[5] += bfhi(u.z);
                acc[6] += bflo(u.w); acc[7] += bfhi(u.w);
            }
        }
    }
    #pragma unroll
    for (int off = 8; off < 64; off <<= 1)
        #pragma unroll
        for (int q = 0; q < 8; ++q) acc[q] += __shfl_xor(acc[q], off);

    float pj[8];
    #pragma unroll
    for (int j = 0; j < 8; ++j) pj[j] = 0.f;

    if (lane < 8) {
        float deg = (float)(s1 - s0 + 1);
        float4 e4 = eagg4[n];
        const float* aip = AI2 + (size_t)n * 64 + lane * 8;
        float4 aiA = *(const float4*)(aip);
        float4 aiB = *(const float4*)(aip + 4);
        uint4 su = *(const uint4*)(AJ2 + (size_t)n * 64 + lane * 8);
        float ajs[8] = { bflo(su.x), bfhi(su.x), bflo(su.y), bfhi(su.y),
                         bflo(su.z), bfhi(su.z), bflo(su.w), bfhi(su.w) };
        float4 bA = *(const float4*)(b2 + lane * 8);
        float4 bB = *(const float4*)(b2 + lane * 8 + 4);
        float av[8] = { aiA.x, aiA.y, aiA.z, aiA.w, aiB.x, aiB.y, aiB.z, aiB.w };
        float bv[8] = { bA.x, bA.y, bA.z, bA.w, bB.x, bB.y, bB.z, bB.w };
        float r[8];
        #pragma unroll
        for (int q = 0; q < 8; ++q) {
            int c = lane * 8 + q;
            float we = sWe[c * 3] * e4.x + sWe[c * 3 + 1] * e4.y + sWe[c * 3 + 2] * e4.z;
            r[q] = fmaxf(deg * (av[q] + bv[q]) + ajs[q] + we + acc[q], 0.f);
        }
        #pragma unroll
        for (int j = 0; j < 8; ++j) {
            float s = 0.f;
            #pragma unroll
            for (int q = 0; q < 8; ++q) s += r[q] * sAB[j * 64 + lane * 8 + q];
            pj[j] = s;
        }
    }
    #pragma unroll
    for (int off = 1; off < 8; off <<= 1)
        #pragma unroll
        for (int j = 0; j < 8; ++j) pj[j] += __shfl_xor(pj[j], off);

    if (lane == 0) {
        *(float4*)(U + (size_t)n * 4) = make_float4(pj[0], pj[1], pj[2], pj[3]);
        *(float4*)(Z + (size_t)n * 4) = make_float4(pj[4], pj[5], pj[6], pj[7]);
    }
}

// ---- final: wave per node, lane per edge, sum Z[src] + log_softmax --------

__global__ __launch_bounds__(256) void final_softmax(
    const float* __restrict__ U, const float* __restrict__ Z,
    const float4* __restrict__ eagg4, const int* __restrict__ rowstart,
    const uint2* __restrict__ csrp, const float* __restrict__ consts,
    float* __restrict__ out, int n_nodes)
{
    int wave = threadIdx.x >> 6, lane = threadIdx.x & 63;
    int n = blockIdx.x * 4 + wave;
    if (n >= n_nodes) return;

    int s0 = rowstart[n], s1 = rowstart[n + 1];
    float ax = 0.f, ay = 0.f, az = 0.f, aw = 0.f;
    for (int i = s0 + lane; i < s1; i += 64) {
        int s = (int)(csrp[i].y >> 16);
        float4 z = *(const float4*)(Z + (size_t)s * 4);
        ax += z.x; ay += z.y; az += z.z; aw += z.w;
    }
    #pragma unroll
    for (int off = 1; off < 64; off <<= 1) {
        ax += __shfl_xor(ax, off); ay += __shfl_xor(ay, off);
        az += __shfl_xor(az, off); aw += __shfl_xor(aw, off);
    }
    if (lane != 0) return;

    float deg = (float)(s1 - s0 + 1);
    float4 u = *(const float4*)(U + (size_t)n * 4);
    float4 zs = *(const float4*)(Z + (size_t)n * 4);   // self-loop term
    float4 e4 = eagg4[n];
    float av[4] = { ax + zs.x, ay + zs.y, az + zs.z, aw + zs.w };
    float uv[4] = { u.x, u.y, u.z, u.w };
    float lg[4];
    #pragma unroll
    for (int j = 0; j < 4; ++j) {
        lg[j] = deg * (uv[j] + consts[j]) + av[j] + consts[4 + j]
              + consts[8 + j * 3] * e4.x + consts[9 + j * 3] * e4.y
              + consts[10 + j * 3] * e4.z;
    }
    float m = fmaxf(fmaxf(lg[0], lg[1]), fmaxf(lg[2], lg[3]));
    float lse = logf(expf(lg[0] - m) + expf(lg[1] - m) + expf(lg[2] - m) + expf(lg[3] - m));
    *(float4*)(out + (size_t)n * 4) =
        make_float4(lg[0] - m - lse, lg[1] - m - lse, lg[2] - m - lse, lg[3] - m - lse);
}

// ---------------------------------------------------------------------------

extern "C" void kernel_launch(void* const* d_in, const int* in_sizes, int n_in,
                              void* d_out, int out_size, void* d_ws, size_t ws_size,
                              hipStream_t stream)
{
    const float* x    = (const float*)d_in[0];
    const int*   ei   = (const int*)  d_in[1];
    const float* ea   = (const float*)d_in[2];
    const float* W1   = (const float*)d_in[3];
    const float* b1   = (const float*)d_in[4];
    const float* W2   = (const float*)d_in[5];
    const float* b2   = (const float*)d_in[6];
    const float* W3   = (const float*)d_in[7];
    const float* b3   = (const float*)d_in[8];
    const float* Wc   = (const float*)d_in[9];
    const float* bc   = (const float*)d_in[10];
    float* out = (float*)d_out;

    const int N = in_sizes[0] / 3;
    const int E = in_sizes[1] / 2;

    char* ws = (char*)d_ws;
    size_t off = 0;
    int*    count    = (int*)(ws + off);            off = align256(off + (size_t)N * 4);
    int*    pos      = (int*)(ws + off);            off = align256(off + (size_t)E * 4);
    int*    rowstart = (int*)(ws + off);            off = align256(off + (size_t)(N + 1) * 4);
    uint2*  csrp     = (uint2*)(ws + off);          off = align256(off + (size_t)E * 8);
    int*    bsum     = (int*)(ws + off);            off = align256(off + 256);
    int*    bexcl    = (int*)(ws + off);            off = align256(off + 256);
    float*  AB       = (float*)(ws + off);          off = align256(off + 512 * 4);
    float*  consts   = (float*)(ws + off);          off = align256(off + 32 * 4);
    float4* eagg4    = (float4*)(ws + off);         off = align256(off + (size_t)N * 16);
    float*  h1buf    = (float*)(ws + off);          off = align256(off + (size_t)N * 128 * 4);
    float*  AI2      = (float*)(ws + off);          off = align256(off + (size_t)N * 64 * 4);
    unsigned short* AJ2 = (unsigned short*)(ws + off); off = align256(off + (size_t)N * 64 * 2);
    float*  Ubuf     = (float*)(ws + off);          off = align256(off + (size_t)N * 16);
    float*  Zbuf     = (float*)(ws + off);          off = align256(off + (size_t)N * 16);
    (void)ws_size;

    hipMemsetAsync(count, 0, (size_t)N * 4, stream);

    const int eb4 = ((E + 3) / 4 + 255) / 256;
    build_count<<<eb4, 256, 0, stream>>>(ei, count, pos, E);

    const int nb1 = (N + 1023) / 1024;
    scan_pass1<<<nb1, 256, 0, stream>>>(count, rowstart, bsum, N);
    scan_pass2<<<1, 64, 0, stream>>>(bsum, bexcl, nb1);
    scan_pass3<<<(N + 1 + 255) / 256, 256, 0, stream>>>(rowstart, bexcl, N);
    csr_scatter<<<eb4, 256, 0, stream>>>(ei, ea, pos, rowstart, csrp, E);

    prep_collapse<<<1, 256, 0, stream>>>(W3, b3, Wc, bc, AB, consts);

    // layer 1 fused: aggregate x/ea per node + node-local matvec -> h1, eagg
    h1_fused<<<(N + 3) / 4, 256, 0, stream>>>(x, W1, b1, rowstart, csrp, eagg4, h1buf, N);

    // layer 2: GEMM -> AI2 (fp32) + AJ2 (bf16); gather+relu+project -> U,Z
    const int mt = (N + 63) / 64;
    gemm_tile<128, 64, 64><<<dim3(mt, 2), 256, 0, stream>>>(h1buf, W2, AI2, AJ2, N);
    gather2<<<(N + 3) / 4, 256, 0, stream>>>(AI2, AJ2, W2, b2, eagg4, rowstart, csrp, AB, Ubuf, Zbuf, N);

    // collapsed layer 3 + classifier + log_softmax
    final_softmax<<<(N + 3) / 4, 256, 0, stream>>>(Ubuf, Zbuf, eagg4, rowstart, csrp, consts, out, N);
}

// Round 7
// 235.635 us; speedup vs baseline: 3.5032x; 1.2135x over previous
//
#include <hip/hip_runtime.h>
#include <math.h>

// ---------------------------------------------------------------------------
// GCN (EdgeConv x3 + classifier + log_softmax) on MI355X.
// R7: 8-lanes-per-node / 8-nodes-per-wave for all gather-style kernels.
// gather2: one AJ2 row (128 B) = 8 lanes x 16 B, so each lane owns 8 channels
// of its node's sum -> no channel shuffle-reduce, 8 independent row-load
// streams per wave. h1_fused / final_softmax same grouping (3-level reduce).
// Packed CSR uint2/edge {bf16 ea0|ea1, bf16 ea2|src<<16} (R6); layer-1
// aggregation pre-linear (R5); layer3+classifier collapsed into Z (R4).
// ---------------------------------------------------------------------------

static inline size_t align256(size_t x) { return (x + 255) & ~size_t(255); }

__device__ inline unsigned short f2bf(float f) {
    unsigned u = __float_as_uint(f);
    unsigned r = (u + 0x7fffu + ((u >> 16) & 1u)) >> 16;
    return (unsigned short)r;
}
__device__ inline float bflo(unsigned u) { return __uint_as_float(u << 16); }
__device__ inline float bfhi(unsigned u) { return __uint_as_float(u & 0xffff0000u); }

// ---- CSR build ------------------------------------------------------------

__global__ __launch_bounds__(256) void build_count(
    const int* __restrict__ ei, int* __restrict__ count,
    int* __restrict__ pos, int E)
{
    int e4 = (blockIdx.x * 256 + threadIdx.x) * 4;
    if (e4 >= E) return;
    if (e4 + 3 < E) {
        int4 d = *(const int4*)(ei + E + e4);
        int4 po;
        po.x = atomicAdd(&count[d.x], 1);
        po.y = atomicAdd(&count[d.y], 1);
        po.z = atomicAdd(&count[d.z], 1);
        po.w = atomicAdd(&count[d.w], 1);
        *(int4*)(pos + e4) = po;
    } else {
        for (int e = e4; e < E; ++e)
            pos[e] = atomicAdd(&count[ei[E + e]], 1);
    }
}

__global__ __launch_bounds__(256) void scan_pass1(
    const int* __restrict__ count, int* __restrict__ rowstart,
    int* __restrict__ bsum, int n)
{
    __shared__ int sh[256];
    const int tid = threadIdx.x;
    const int base = blockIdx.x * 1024 + tid * 4;
    int v0 = 0, v1 = 0, v2 = 0, v3 = 0;
    if (base + 3 < n) {
        int4 c = *(const int4*)(count + base);
        v0 = c.x; v1 = c.y; v2 = c.z; v3 = c.w;
    } else {
        if (base + 0 < n) v0 = count[base + 0];
        if (base + 1 < n) v1 = count[base + 1];
        if (base + 2 < n) v2 = count[base + 2];
        if (base + 3 < n) v3 = count[base + 3];
    }
    int tsum = v0 + v1 + v2 + v3;
    sh[tid] = tsum;
    __syncthreads();
    for (int off = 1; off < 256; off <<= 1) {
        int t = (tid >= off) ? sh[tid - off] : 0;
        __syncthreads();
        sh[tid] += t;
        __syncthreads();
    }
    int excl = sh[tid] - tsum;
    int p0 = excl + v0, p1 = p0 + v1, p2 = p1 + v2, p3 = p2 + v3;
    if (base + 0 < n) rowstart[base + 1] = p0;
    if (base + 1 < n) rowstart[base + 2] = p1;
    if (base + 2 < n) rowstart[base + 3] = p2;
    if (base + 3 < n) rowstart[base + 4] = p3;
    if (tid == 255) bsum[blockIdx.x] = sh[255];
}

__global__ __launch_bounds__(64) void scan_pass2(
    const int* __restrict__ bsum, int* __restrict__ bexcl, int nb)
{
    int lane = threadIdx.x;
    int own = (lane < nb) ? bsum[lane] : 0;
    int x = own;
    for (int off = 1; off < 64; off <<= 1) {
        int t = __shfl_up(x, off);
        if (lane >= off) x += t;
    }
    bexcl[lane] = x - own;
}

__global__ __launch_bounds__(256) void scan_pass3(
    int* __restrict__ rowstart, const int* __restrict__ bexcl, int n)
{
    int j = blockIdx.x * 256 + threadIdx.x;
    if (j > n) return;
    if (j == 0) { rowstart[0] = 0; return; }
    int b = (j - 1) >> 10;
    if (b > 0) rowstart[j] += bexcl[b];
}

// scatter packed edge record: {bf16 e0 | bf16 e1 << 16, bf16 e2 | src << 16}
__global__ __launch_bounds__(256) void csr_scatter(
    const int* __restrict__ ei, const float* __restrict__ ea,
    const int* __restrict__ pos, const int* __restrict__ rowstart,
    uint2* __restrict__ csrp, int E)
{
    int e4 = (blockIdx.x * 256 + threadIdx.x) * 4;
    if (e4 >= E) return;
    if (e4 + 3 < E) {
        int4 s = *(const int4*)(ei + e4);
        int4 d = *(const int4*)(ei + E + e4);
        int4 po = *(const int4*)(pos + e4);
        float4 a = *(const float4*)(ea + (size_t)e4 * 3);
        float4 b = *(const float4*)(ea + (size_t)e4 * 3 + 4);
        float4 c = *(const float4*)(ea + (size_t)e4 * 3 + 8);
        float ev[12] = { a.x, a.y, a.z, a.w, b.x, b.y, b.z, b.w, c.x, c.y, c.z, c.w };
        int sv[4] = { s.x, s.y, s.z, s.w };
        int dv[4] = { d.x, d.y, d.z, d.w };
        int pv[4] = { po.x, po.y, po.z, po.w };
        #pragma unroll
        for (int r = 0; r < 4; ++r) {
            uint2 p;
            p.x = (unsigned)f2bf(ev[r * 3 + 0]) | ((unsigned)f2bf(ev[r * 3 + 1]) << 16);
            p.y = (unsigned)f2bf(ev[r * 3 + 2]) | ((unsigned)sv[r] << 16);
            csrp[rowstart[dv[r]] + pv[r]] = p;
        }
    } else {
        for (int e = e4; e < E; ++e) {
            uint2 p;
            p.x = (unsigned)f2bf(ea[e * 3 + 0]) | ((unsigned)f2bf(ea[e * 3 + 1]) << 16);
            p.y = (unsigned)f2bf(ea[e * 3 + 2]) | ((unsigned)ei[e] << 16);
            csrp[rowstart[ei[E + e]] + pos[e]] = p;
        }
    }
}

// ---- precompute collapsed layer-3 matrices --------------------------------

__global__ __launch_bounds__(256) void prep_collapse(
    const float* __restrict__ W3, const float* __restrict__ b3,
    const float* __restrict__ Wc, const float* __restrict__ bc,
    float* __restrict__ AB, float* __restrict__ consts)
{
    int t = threadIdx.x;
    for (int idx = t; idx < 512; idx += 256) {
        int j = idx >> 6, k = idx & 63;
        int jj = j & 3;
        int base = (j >= 4) ? 64 : 0;
        float s = 0.f;
        #pragma unroll
        for (int c = 0; c < 32; ++c)
            s += Wc[jj * 32 + c] * W3[c * 131 + base + k];
        AB[idx] = s;
    }
    if (t < 4) {
        float db = 0.f;
        for (int c = 0; c < 32; ++c) db += Wc[t * 32 + c] * b3[c];
        consts[t] = db;
        consts[4 + t] = bc[t];
        for (int q = 0; q < 3; ++q) {
            float s = 0.f;
            for (int c = 0; c < 32; ++c) s += Wc[t * 32 + c] * W3[c * 131 + 128 + q];
            consts[8 + t * 3 + q] = s;
        }
    }
}

// ---- fused layer-1: 8 lanes/node, 8 nodes/wave ----------------------------
// h1 = relu([deg*x, x+xagg, eagg, deg] @ [Wi1|Wj1|We1|b1]^T)

__global__ __launch_bounds__(256) void h1_fused(
    const float* __restrict__ x, const float* __restrict__ W1,
    const float* __restrict__ b1, const int* __restrict__ rowstart,
    const uint2* __restrict__ csrp, float4* __restrict__ eagg4,
    float* __restrict__ h1, int n_nodes)
{
    __shared__ float sM[10 * 128];
    const int tid = threadIdx.x;
    for (int t = tid; t < 1280; t += 256) {
        int k = t >> 7, c = t & 127;
        sM[t] = (k < 9) ? W1[c * 9 + k] : b1[c];
    }
    __syncthreads();

    int wl = tid & 63;
    int grp = wl >> 3, ch8 = wl & 7;
    int n = blockIdx.x * 32 + (tid >> 6) * 8 + grp;
    if (n >= n_nodes) return;

    int s0 = rowstart[n], s1 = rowstart[n + 1];
    float xx = 0.f, xy = 0.f, xz = 0.f, ex = 0.f, ey = 0.f, ez = 0.f;
    for (int i = s0 + ch8; i < s1; i += 8) {
        uint2 p = csrp[i];
        int s = (int)(p.y >> 16);
        ex += bflo(p.x); ey += bfhi(p.x); ez += bflo(p.y);
        const float* xp = x + (size_t)s * 3;
        xx += xp[0]; xy += xp[1]; xz += xp[2];
    }
    #pragma unroll
    for (int off = 1; off < 8; off <<= 1) {
        xx += __shfl_xor(xx, off); xy += __shfl_xor(xy, off); xz += __shfl_xor(xz, off);
        ex += __shfl_xor(ex, off); ey += __shfl_xor(ey, off); ez += __shfl_xor(ez, off);
    }

    float deg = (float)(s1 - s0 + 1);
    float x0 = x[n * 3], x1 = x[n * 3 + 1], x2 = x[n * 3 + 2];
    float v[10] = { deg * x0, deg * x1, deg * x2,
                    x0 + xx, x1 + xy, x2 + xz,
                    ex, ey, ez, deg };
    int cb = ch8 * 16;
    #pragma unroll
    for (int q4 = 0; q4 < 4; ++q4) {
        float4 h4 = make_float4(0.f, 0.f, 0.f, 0.f);
        #pragma unroll
        for (int k = 0; k < 10; ++k) {
            float4 m4 = *(const float4*)(sM + k * 128 + cb + q4 * 4);
            h4.x += v[k] * m4.x; h4.y += v[k] * m4.y;
            h4.z += v[k] * m4.z; h4.w += v[k] * m4.w;
        }
        h4.x = fmaxf(h4.x, 0.f); h4.y = fmaxf(h4.y, 0.f);
        h4.z = fmaxf(h4.z, 0.f); h4.w = fmaxf(h4.w, 0.f);
        *(float4*)(h1 + (size_t)n * 128 + cb + q4 * 4) = h4;
    }
    if (ch8 == 0) eagg4[n] = make_float4(ex, ey, ez, 0.f);
}

// ---- register-blocked GEMM: cols 0-63 -> AI2 fp32, 64-127 -> AJ2 bf16 -----

template <int FIN, int NCB, int FOUT>
__global__ __launch_bounds__(256) void gemm_tile(
    const float* __restrict__ x, const float* __restrict__ W,
    float* __restrict__ AI2, unsigned short* __restrict__ AJ2, int n_nodes)
{
    constexpr int WROW = 2 * FIN + 3;
    __shared__ float sX[64 * FIN];
    __shared__ float sW[NCB * FIN];

    const int tid = threadIdx.x;
    const int tx = tid & 15;
    const int ty = tid >> 4;
    const int mbase = blockIdx.x * 64;
    const int jbase = blockIdx.y * NCB;

    constexpr int XT = 16 * FIN;
    for (int t = tid; t < XT; t += 256) {
        int r = t & 63, ch = t >> 6;
        int gn = mbase + r;
        float4 v = make_float4(0.f, 0.f, 0.f, 0.f);
        if (gn < n_nodes) v = *(const float4*)(x + (size_t)gn * FIN + ch * 4);
        *(float4*)(sX + (ch * 64 + r) * 4) = v;
    }
    for (int t = tid; t < NCB * FIN; t += 256) {
        int j = t / FIN, k = t % FIN;
        int jg = jbase + j;
        float w = (jg < FOUT) ? W[jg * WROW + k] : W[(jg - FOUT) * WROW + FIN + k];
        sW[((k >> 2) * NCB + j) * 4 + (k & 3)] = w;
    }
    __syncthreads();

    float acc[4][4];
    #pragma unroll
    for (int i = 0; i < 4; ++i)
        #pragma unroll
        for (int jj = 0; jj < 4; ++jj) acc[i][jj] = 0.f;

    #pragma unroll 2
    for (int k0 = 0; k0 < FIN; k0 += 4) {
        float4 a[4], bb[4];
        #pragma unroll
        for (int i = 0; i < 4; ++i)
            a[i] = *(const float4*)(sX + ((k0 >> 2) * 64 + (ty * 4 + i)) * 4);
        #pragma unroll
        for (int i = 0; i < 4; ++i)
            bb[i] = *(const float4*)(sW + ((k0 >> 2) * NCB + (tx + 16 * i)) * 4);
        #pragma unroll
        for (int mi = 0; mi < 4; ++mi)
            #pragma unroll
            for (int ji = 0; ji < 4; ++ji)
                acc[mi][ji] += a[mi].x * bb[ji].x + a[mi].y * bb[ji].y
                             + a[mi].z * bb[ji].z + a[mi].w * bb[ji].w;
    }

    if (blockIdx.y == 0) {
        #pragma unroll
        for (int mi = 0; mi < 4; ++mi) {
            int gn = mbase + ty * 4 + mi;
            if (gn >= n_nodes) continue;
            #pragma unroll
            for (int ji = 0; ji < 4; ++ji)
                AI2[(size_t)gn * 64 + tx + 16 * ji] = acc[mi][ji];
        }
    } else {
        #pragma unroll
        for (int mi = 0; mi < 4; ++mi) {
            int gn = mbase + ty * 4 + mi;
            if (gn >= n_nodes) continue;
            #pragma unroll
            for (int ji = 0; ji < 4; ++ji)
                AJ2[(size_t)gn * 64 + tx + 16 * ji] = f2bf(acc[mi][ji]);
        }
    }
}

// ---- layer-2 gather: 8 lanes/node, 8 nodes/wave, lane owns 8 channels -----

__global__ __launch_bounds__(256) void gather2(
    const float* __restrict__ AI2, const unsigned short* __restrict__ AJ2,
    const float* __restrict__ W2, const float* __restrict__ b2,
    const float4* __restrict__ eagg4, const int* __restrict__ rowstart,
    const uint2* __restrict__ csrp, const float* __restrict__ AB,
    float* __restrict__ U, float* __restrict__ Z, int n_nodes)
{
    __shared__ float sAB[512];
    __shared__ float sWe[192];
    const int tid = threadIdx.x;
    for (int t = tid; t < 512; t += 256) sAB[t] = AB[t];
    for (int t = tid; t < 192; t += 256) {
        int c = t / 3, q = t % 3;
        sWe[t] = W2[c * 259 + 256 + q];
    }
    __syncthreads();

    int wl = tid & 63;
    int grp = wl >> 3, ch8 = wl & 7;
    int n = blockIdx.x * 32 + (tid >> 6) * 8 + grp;
    if (n >= n_nodes) return;

    int s0 = rowstart[n], s1 = rowstart[n + 1];
    int trip = s1 - s0;

    float acc[8];
    #pragma unroll
    for (int q = 0; q < 8; ++q) acc[q] = 0.f;

    int myidx = 0;
    for (int it = 0; it < trip; ++it) {
        if ((it & 7) == 0) {
            int j = s0 + it + ch8;
            if (j >= s1) j = s1 - 1;       // clamped lanes never consumed
            myidx = (int)(csrp[j].y >> 16);
        }
        int s = __shfl(myidx, grp * 8 + (it & 7));
        uint4 u = *(const uint4*)(AJ2 + (size_t)s * 64 + ch8 * 8);
        acc[0] += bflo(u.x); acc[1] += bfhi(u.x);
        acc[2] += bflo(u.y); acc[3] += bfhi(u.y);
        acc[4] += bflo(u.z); acc[5] += bfhi(u.z);
        acc[6] += bflo(u.w); acc[7] += bfhi(u.w);
    }

    // epilogue: every lane handles its 8 channels c = ch8*8 + q
    float deg = (float)(trip + 1);
    float4 e4 = eagg4[n];
    const float* aip = AI2 + (size_t)n * 64 + ch8 * 8;
    float4 aiA = *(const float4*)(aip);
    float4 aiB = *(const float4*)(aip + 4);
    uint4 su = *(const uint4*)(AJ2 + (size_t)n * 64 + ch8 * 8);
    float ajs[8] = { bflo(su.x), bfhi(su.x), bflo(su.y), bfhi(su.y),
                     bflo(su.z), bfhi(su.z), bflo(su.w), bfhi(su.w) };
    float4 bA = *(const float4*)(b2 + ch8 * 8);
    float4 bB = *(const float4*)(b2 + ch8 * 8 + 4);
    float av[8] = { aiA.x, aiA.y, aiA.z, aiA.w, aiB.x, aiB.y, aiB.z, aiB.w };
    float bv[8] = { bA.x, bA.y, bA.z, bA.w, bB.x, bB.y, bB.z, bB.w };
    float r[8];
    #pragma unroll
    for (int q = 0; q < 8; ++q) {
        int c = ch8 * 8 + q;
        float we = sWe[c * 3] * e4.x + sWe[c * 3 + 1] * e4.y + sWe[c * 3 + 2] * e4.z;
        r[q] = fmaxf(deg * (av[q] + bv[q]) + ajs[q] + we + acc[q], 0.f);
    }
    float pj[8];
    #pragma unroll
    for (int j = 0; j < 8; ++j) {
        float4 wA = *(const float4*)(sAB + j * 64 + ch8 * 8);
        float4 wB = *(const float4*)(sAB + j * 64 + ch8 * 8 + 4);
        pj[j] = r[0] * wA.x + r[1] * wA.y + r[2] * wA.z + r[3] * wA.w
              + r[4] * wB.x + r[5] * wB.y + r[6] * wB.z + r[7] * wB.w;
    }
    #pragma unroll
    for (int off = 1; off < 8; off <<= 1)
        #pragma unroll
        for (int j = 0; j < 8; ++j) pj[j] += __shfl_xor(pj[j], off);

    if (ch8 == 0) {
        *(float4*)(U + (size_t)n * 4) = make_float4(pj[0], pj[1], pj[2], pj[3]);
        *(float4*)(Z + (size_t)n * 4) = make_float4(pj[4], pj[5], pj[6], pj[7]);
    }
}

// ---- final: 8 lanes/node, 8 nodes/wave, sum Z[src] + log_softmax ----------

__global__ __launch_bounds__(256) void final_softmax(
    const float* __restrict__ U, const float* __restrict__ Z,
    const float4* __restrict__ eagg4, const int* __restrict__ rowstart,
    const uint2* __restrict__ csrp, const float* __restrict__ consts,
    float* __restrict__ out, int n_nodes)
{
    int wl = threadIdx.x & 63;
    int grp = wl >> 3, ch8 = wl & 7;
    int n = blockIdx.x * 32 + (threadIdx.x >> 6) * 8 + grp;
    if (n >= n_nodes) return;

    int s0 = rowstart[n], s1 = rowstart[n + 1];
    float ax = 0.f, ay = 0.f, az = 0.f, aw = 0.f;
    for (int i = s0 + ch8; i < s1; i += 8) {
        int s = (int)(csrp[i].y >> 16);
        float4 z = *(const float4*)(Z + (size_t)s * 4);
        ax += z.x; ay += z.y; az += z.z; aw += z.w;
    }
    #pragma unroll
    for (int off = 1; off < 8; off <<= 1) {
        ax += __shfl_xor(ax, off); ay += __shfl_xor(ay, off);
        az += __shfl_xor(az, off); aw += __shfl_xor(aw, off);
    }
    if (ch8 != 0) return;

    float deg = (float)(s1 - s0 + 1);
    float4 u = *(const float4*)(U + (size_t)n * 4);
    float4 zs = *(const float4*)(Z + (size_t)n * 4);   // self-loop term
    float4 e4 = eagg4[n];
    float av[4] = { ax + zs.x, ay + zs.y, az + zs.z, aw + zs.w };
    float uv[4] = { u.x, u.y, u.z, u.w };
    float lg[4];
    #pragma unroll
    for (int j = 0; j < 4; ++j) {
        lg[j] = deg * (uv[j] + consts[j]) + av[j] + consts[4 + j]
              + consts[8 + j * 3] * e4.x + consts[9 + j * 3] * e4.y
              + consts[10 + j * 3] * e4.z;
    }
    float m = fmaxf(fmaxf(lg[0], lg[1]), fmaxf(lg[2], lg[3]));
    float lse = logf(expf(lg[0] - m) + expf(lg[1] - m) + expf(lg[2] - m) + expf(lg[3] - m));
    *(float4*)(out + (size_t)n * 4) =
        make_float4(lg[0] - m - lse, lg[1] - m - lse, lg[2] - m - lse, lg[3] - m - lse);
}

// ---------------------------------------------------------------------------

extern "C" void kernel_launch(void* const* d_in, const int* in_sizes, int n_in,
                              void* d_out, int out_size, void* d_ws, size_t ws_size,
                              hipStream_t stream)
{
    const float* x    = (const float*)d_in[0];
    const int*   ei   = (const int*)  d_in[1];
    const float* ea   = (const float*)d_in[2];
    const float* W1   = (const float*)d_in[3];
    const float* b1   = (const float*)d_in[4];
    const float* W2   = (const float*)d_in[5];
    const float* b2   = (const float*)d_in[6];
    const float* W3   = (const float*)d_in[7];
    const float* b3   = (const float*)d_in[8];
    const float* Wc   = (const float*)d_in[9];
    const float* bc   = (const float*)d_in[10];
    float* out = (float*)d_out;

    const int N = in_sizes[0] / 3;
    const int E = in_sizes[1] / 2;

    char* ws = (char*)d_ws;
    size_t off = 0;
    int*    count    = (int*)(ws + off);            off = align256(off + (size_t)N * 4);
    int*    pos      = (int*)(ws + off);            off = align256(off + (size_t)E * 4);
    int*    rowstart = (int*)(ws + off);            off = align256(off + (size_t)(N + 1) * 4);
    uint2*  csrp     = (uint2*)(ws + off);          off = align256(off + (size_t)E * 8);
    int*    bsum     = (int*)(ws + off);            off = align256(off + 256);
    int*    bexcl    = (int*)(ws + off);            off = align256(off + 256);
    float*  AB       = (float*)(ws + off);          off = align256(off + 512 * 4);
    float*  consts   = (float*)(ws + off);          off = align256(off + 32 * 4);
    float4* eagg4    = (float4*)(ws + off);         off = align256(off + (size_t)N * 16);
    float*  h1buf    = (float*)(ws + off);          off = align256(off + (size_t)N * 128 * 4);
    float*  AI2      = (float*)(ws + off);          off = align256(off + (size_t)N * 64 * 4);
    unsigned short* AJ2 = (unsigned short*)(ws + off); off = align256(off + (size_t)N * 64 * 2);
    float*  Ubuf     = (float*)(ws + off);          off = align256(off + (size_t)N * 16);
    float*  Zbuf     = (float*)(ws + off);          off = align256(off + (size_t)N * 16);
    (void)ws_size;

    hipMemsetAsync(count, 0, (size_t)N * 4, stream);

    const int eb4 = ((E + 3) / 4 + 255) / 256;
    build_count<<<eb4, 256, 0, stream>>>(ei, count, pos, E);

    const int nb1 = (N + 1023) / 1024;
    scan_pass1<<<nb1, 256, 0, stream>>>(count, rowstart, bsum, N);
    scan_pass2<<<1, 64, 0, stream>>>(bsum, bexcl, nb1);
    scan_pass3<<<(N + 1 + 255) / 256, 256, 0, stream>>>(rowstart, bexcl, N);
    csr_scatter<<<eb4, 256, 0, stream>>>(ei, ea, pos, rowstart, csrp, E);

    prep_collapse<<<1, 256, 0, stream>>>(W3, b3, Wc, bc, AB, consts);

    const int gb = (N + 31) / 32;

    // layer 1 fused: aggregate x/ea per node + node-local matvec -> h1, eagg
    h1_fused<<<gb, 256, 0, stream>>>(x, W1, b1, rowstart, csrp, eagg4, h1buf, N);

    // layer 2: GEMM -> AI2 (fp32) + AJ2 (bf16); gather+relu+project -> U,Z
    const int mt = (N + 63) / 64;
    gemm_tile<128, 64, 64><<<dim3(mt, 2), 256, 0, stream>>>(h1buf, W2, AI2, AJ2, N);
    gather2<<<gb, 256, 0, stream>>>(AI2, AJ2, W2, b2, eagg4, rowstart, csrp, AB, Ubuf, Zbuf, N);

    // collapsed layer 3 + classifier + log_softmax
    final_softmax<<<gb, 256, 0, stream>>>(Ubuf, Zbuf, eagg4, rowstart, csrp, consts, out, N);
}

// Round 8
// 203.366 us; speedup vs baseline: 4.0590x; 1.1587x over previous
//
#include <hip/hip_runtime.h>
#include <math.h>

// ---------------------------------------------------------------------------
// GCN (EdgeConv x3 + classifier + log_softmax) on MI355X.
// R8: layer-2 GEMM moved to MFMA (v_mfma_f32_16x16x32_bf16): h1 stored bf16
// by h1_fused, W2 staged bf16 in LDS [col][k] pad+8. A-frags loaded straight
// from global (A[m=lane&15][k=quad*8+j]); C/D col=lane&15,row=quad*4+reg.
// Everything else: R7 structure (8 lanes/node gathers, packed CSR, collapsed
// layer 3, pre-linear layer-1 aggregation).
// ---------------------------------------------------------------------------

static inline size_t align256(size_t x) { return (x + 255) & ~size_t(255); }

typedef unsigned short ushort_t;
using frag8  = __attribute__((ext_vector_type(8))) short;   // 8 bf16 (4 VGPR)
using f32x4v = __attribute__((ext_vector_type(4))) float;   // 4 fp32 acc

__device__ inline unsigned short f2bf(float f) {
    unsigned u = __float_as_uint(f);
    unsigned r = (u + 0x7fffu + ((u >> 16) & 1u)) >> 16;
    return (unsigned short)r;
}
__device__ inline float bflo(unsigned u) { return __uint_as_float(u << 16); }
__device__ inline float bfhi(unsigned u) { return __uint_as_float(u & 0xffff0000u); }

// ---- CSR build ------------------------------------------------------------

__global__ __launch_bounds__(256) void build_count(
    const int* __restrict__ ei, int* __restrict__ count,
    int* __restrict__ pos, int E)
{
    int e4 = (blockIdx.x * 256 + threadIdx.x) * 4;
    if (e4 >= E) return;
    if (e4 + 3 < E) {
        int4 d = *(const int4*)(ei + E + e4);
        int4 po;
        po.x = atomicAdd(&count[d.x], 1);
        po.y = atomicAdd(&count[d.y], 1);
        po.z = atomicAdd(&count[d.z], 1);
        po.w = atomicAdd(&count[d.w], 1);
        *(int4*)(pos + e4) = po;
    } else {
        for (int e = e4; e < E; ++e)
            pos[e] = atomicAdd(&count[ei[E + e]], 1);
    }
}

__global__ __launch_bounds__(256) void scan_pass1(
    const int* __restrict__ count, int* __restrict__ rowstart,
    int* __restrict__ bsum, int n)
{
    __shared__ int sh[256];
    const int tid = threadIdx.x;
    const int base = blockIdx.x * 1024 + tid * 4;
    int v0 = 0, v1 = 0, v2 = 0, v3 = 0;
    if (base + 3 < n) {
        int4 c = *(const int4*)(count + base);
        v0 = c.x; v1 = c.y; v2 = c.z; v3 = c.w;
    } else {
        if (base + 0 < n) v0 = count[base + 0];
        if (base + 1 < n) v1 = count[base + 1];
        if (base + 2 < n) v2 = count[base + 2];
        if (base + 3 < n) v3 = count[base + 3];
    }
    int tsum = v0 + v1 + v2 + v3;
    sh[tid] = tsum;
    __syncthreads();
    for (int off = 1; off < 256; off <<= 1) {
        int t = (tid >= off) ? sh[tid - off] : 0;
        __syncthreads();
        sh[tid] += t;
        __syncthreads();
    }
    int excl = sh[tid] - tsum;
    int p0 = excl + v0, p1 = p0 + v1, p2 = p1 + v2, p3 = p2 + v3;
    if (base + 0 < n) rowstart[base + 1] = p0;
    if (base + 1 < n) rowstart[base + 2] = p1;
    if (base + 2 < n) rowstart[base + 3] = p2;
    if (base + 3 < n) rowstart[base + 4] = p3;
    if (tid == 255) bsum[blockIdx.x] = sh[255];
}

__global__ __launch_bounds__(64) void scan_pass2(
    const int* __restrict__ bsum, int* __restrict__ bexcl, int nb)
{
    int lane = threadIdx.x;
    int own = (lane < nb) ? bsum[lane] : 0;
    int x = own;
    for (int off = 1; off < 64; off <<= 1) {
        int t = __shfl_up(x, off);
        if (lane >= off) x += t;
    }
    bexcl[lane] = x - own;
}

__global__ __launch_bounds__(256) void scan_pass3(
    int* __restrict__ rowstart, const int* __restrict__ bexcl, int n)
{
    int j = blockIdx.x * 256 + threadIdx.x;
    if (j > n) return;
    if (j == 0) { rowstart[0] = 0; return; }
    int b = (j - 1) >> 10;
    if (b > 0) rowstart[j] += bexcl[b];
}

// scatter packed edge record: {bf16 e0 | bf16 e1 << 16, bf16 e2 | src << 16}
__global__ __launch_bounds__(256) void csr_scatter(
    const int* __restrict__ ei, const float* __restrict__ ea,
    const int* __restrict__ pos, const int* __restrict__ rowstart,
    uint2* __restrict__ csrp, int E)
{
    int e4 = (blockIdx.x * 256 + threadIdx.x) * 4;
    if (e4 >= E) return;
    if (e4 + 3 < E) {
        int4 s = *(const int4*)(ei + e4);
        int4 d = *(const int4*)(ei + E + e4);
        int4 po = *(const int4*)(pos + e4);
        float4 a = *(const float4*)(ea + (size_t)e4 * 3);
        float4 b = *(const float4*)(ea + (size_t)e4 * 3 + 4);
        float4 c = *(const float4*)(ea + (size_t)e4 * 3 + 8);
        float ev[12] = { a.x, a.y, a.z, a.w, b.x, b.y, b.z, b.w, c.x, c.y, c.z, c.w };
        int sv[4] = { s.x, s.y, s.z, s.w };
        int dv[4] = { d.x, d.y, d.z, d.w };
        int pv[4] = { po.x, po.y, po.z, po.w };
        #pragma unroll
        for (int r = 0; r < 4; ++r) {
            uint2 p;
            p.x = (unsigned)f2bf(ev[r * 3 + 0]) | ((unsigned)f2bf(ev[r * 3 + 1]) << 16);
            p.y = (unsigned)f2bf(ev[r * 3 + 2]) | ((unsigned)sv[r] << 16);
            csrp[rowstart[dv[r]] + pv[r]] = p;
        }
    } else {
        for (int e = e4; e < E; ++e) {
            uint2 p;
            p.x = (unsigned)f2bf(ea[e * 3 + 0]) | ((unsigned)f2bf(ea[e * 3 + 1]) << 16);
            p.y = (unsigned)f2bf(ea[e * 3 + 2]) | ((unsigned)ei[e] << 16);
            csrp[rowstart[ei[E + e]] + pos[e]] = p;
        }
    }
}

// ---- precompute collapsed layer-3 matrices --------------------------------

__global__ __launch_bounds__(256) void prep_collapse(
    const float* __restrict__ W3, const float* __restrict__ b3,
    const float* __restrict__ Wc, const float* __restrict__ bc,
    float* __restrict__ AB, float* __restrict__ consts)
{
    int t = threadIdx.x;
    for (int idx = t; idx < 512; idx += 256) {
        int j = idx >> 6, k = idx & 63;
        int jj = j & 3;
        int base = (j >= 4) ? 64 : 0;
        float s = 0.f;
        #pragma unroll
        for (int c = 0; c < 32; ++c)
            s += Wc[jj * 32 + c] * W3[c * 131 + base + k];
        AB[idx] = s;
    }
    if (t < 4) {
        float db = 0.f;
        for (int c = 0; c < 32; ++c) db += Wc[t * 32 + c] * b3[c];
        consts[t] = db;
        consts[4 + t] = bc[t];
        for (int q = 0; q < 3; ++q) {
            float s = 0.f;
            for (int c = 0; c < 32; ++c) s += Wc[t * 32 + c] * W3[c * 131 + 128 + q];
            consts[8 + t * 3 + q] = s;
        }
    }
}

// ---- fused layer-1: 8 lanes/node, 8 nodes/wave; h1 OUT IN BF16 ------------
// h1 = relu([deg*x, x+xagg, eagg, deg] @ [Wi1|Wj1|We1|b1]^T)

__global__ __launch_bounds__(256) void h1_fused(
    const float* __restrict__ x, const float* __restrict__ W1,
    const float* __restrict__ b1, const int* __restrict__ rowstart,
    const uint2* __restrict__ csrp, float4* __restrict__ eagg4,
    ushort_t* __restrict__ h1, int n_nodes)
{
    __shared__ float sM[10 * 128];
    const int tid = threadIdx.x;
    for (int t = tid; t < 1280; t += 256) {
        int k = t >> 7, c = t & 127;
        sM[t] = (k < 9) ? W1[c * 9 + k] : b1[c];
    }
    __syncthreads();

    int wl = tid & 63;
    int grp = wl >> 3, ch8 = wl & 7;
    int n = blockIdx.x * 32 + (tid >> 6) * 8 + grp;
    if (n >= n_nodes) return;

    int s0 = rowstart[n], s1 = rowstart[n + 1];
    float xx = 0.f, xy = 0.f, xz = 0.f, ex = 0.f, ey = 0.f, ez = 0.f;
    for (int i = s0 + ch8; i < s1; i += 8) {
        uint2 p = csrp[i];
        int s = (int)(p.y >> 16);
        ex += bflo(p.x); ey += bfhi(p.x); ez += bflo(p.y);
        const float* xp = x + (size_t)s * 3;
        xx += xp[0]; xy += xp[1]; xz += xp[2];
    }
    #pragma unroll
    for (int off = 1; off < 8; off <<= 1) {
        xx += __shfl_xor(xx, off); xy += __shfl_xor(xy, off); xz += __shfl_xor(xz, off);
        ex += __shfl_xor(ex, off); ey += __shfl_xor(ey, off); ez += __shfl_xor(ez, off);
    }

    float deg = (float)(s1 - s0 + 1);
    float x0 = x[n * 3], x1 = x[n * 3 + 1], x2 = x[n * 3 + 2];
    float v[10] = { deg * x0, deg * x1, deg * x2,
                    x0 + xx, x1 + xy, x2 + xz,
                    ex, ey, ez, deg };
    int cb = ch8 * 16;
    #pragma unroll
    for (int g = 0; g < 2; ++g) {
        float hv[8];
        #pragma unroll
        for (int q = 0; q < 8; ++q) {
            int c = cb + g * 8 + q;
            float h = 0.f;
            #pragma unroll
            for (int k = 0; k < 10; ++k) h += v[k] * sM[k * 128 + c];
            hv[q] = fmaxf(h, 0.f);
        }
        uint4 u;
        u.x = (unsigned)f2bf(hv[0]) | ((unsigned)f2bf(hv[1]) << 16);
        u.y = (unsigned)f2bf(hv[2]) | ((unsigned)f2bf(hv[3]) << 16);
        u.z = (unsigned)f2bf(hv[4]) | ((unsigned)f2bf(hv[5]) << 16);
        u.w = (unsigned)f2bf(hv[6]) | ((unsigned)f2bf(hv[7]) << 16);
        *(uint4*)(h1 + (size_t)n * 128 + cb + g * 8) = u;
    }
    if (ch8 == 0) eagg4[n] = make_float4(ex, ey, ez, 0.f);
}

// ---- MFMA GEMM: [AI2 | AJ2] = h1(bf16) @ W2'(bf16)^T ----------------------
// Block: 256 thr = 4 waves, 64 rows/block (16/wave), all 128 cols.
// W2' staged in LDS as [col][k], k-padded +8 bf16 (2-way max bank alias).
// A loaded from global: A[m=lane&15][k=quad*8+j]. C/D: col=lane&15,
// row=quad*4+reg (verified m89 mapping).

__global__ __launch_bounds__(256) void gemm_mfma(
    const ushort_t* __restrict__ h1, const float* __restrict__ W2,
    float* __restrict__ AI2, ushort_t* __restrict__ AJ2, int n_nodes)
{
    constexpr int KP = 136;                 // 128 + 8 pad (bf16)
    __shared__ ushort_t sB[128 * KP];

    const int tid = threadIdx.x;
    // stage W2' -> bf16 LDS: col jg in [0,128), k in [0,128)
    for (int t = tid; t < 128 * 128; t += 256) {
        int jg = t >> 7, k = t & 127;
        float w = (jg < 64) ? W2[jg * 259 + k] : W2[(jg - 64) * 259 + 128 + k];
        sB[jg * KP + k] = f2bf(w);
    }
    __syncthreads();

    const int wave = tid >> 6, lane = tid & 63;
    const int m = lane & 15, quad = lane >> 4;
    const int mwave = blockIdx.x * 64 + wave * 16;

    int arow = mwave + m;
    int arow_c = arow < n_nodes ? arow : (n_nodes - 1);

    frag8 a[4];
    #pragma unroll
    for (int ks = 0; ks < 4; ++ks)
        a[ks] = *(const frag8*)(h1 + (size_t)arow_c * 128 + ks * 32 + quad * 8);

    f32x4v acc[8];
    #pragma unroll
    for (int t = 0; t < 8; ++t) acc[t] = (f32x4v)(0.f);

    #pragma unroll
    for (int t = 0; t < 8; ++t) {
        #pragma unroll
        for (int ks = 0; ks < 4; ++ks) {
            frag8 b = *(const frag8*)(sB + (t * 16 + m) * KP + ks * 32 + quad * 8);
            acc[t] = __builtin_amdgcn_mfma_f32_16x16x32_bf16(a[ks], b, acc[t], 0, 0, 0);
        }
    }

    #pragma unroll
    for (int reg = 0; reg < 4; ++reg) {
        int grow = mwave + quad * 4 + reg;
        if (grow >= n_nodes) continue;
        #pragma unroll
        for (int t = 0; t < 4; ++t)
            AI2[(size_t)grow * 64 + t * 16 + m] = acc[t][reg];
        #pragma unroll
        for (int t = 4; t < 8; ++t)
            AJ2[(size_t)grow * 64 + (t - 4) * 16 + m] = f2bf(acc[t][reg]);
    }
}

// ---- layer-2 gather: 8 lanes/node, 8 nodes/wave, lane owns 8 channels -----

__global__ __launch_bounds__(256) void gather2(
    const float* __restrict__ AI2, const ushort_t* __restrict__ AJ2,
    const float* __restrict__ W2, const float* __restrict__ b2,
    const float4* __restrict__ eagg4, const int* __restrict__ rowstart,
    const uint2* __restrict__ csrp, const float* __restrict__ AB,
    float* __restrict__ U, float* __restrict__ Z, int n_nodes)
{
    __shared__ float sAB[512];
    __shared__ float sWe[192];
    const int tid = threadIdx.x;
    for (int t = tid; t < 512; t += 256) sAB[t] = AB[t];
    for (int t = tid; t < 192; t += 256) {
        int c = t / 3, q = t % 3;
        sWe[t] = W2[c * 259 + 256 + q];
    }
    __syncthreads();

    int wl = tid & 63;
    int grp = wl >> 3, ch8 = wl & 7;
    int n = blockIdx.x * 32 + (tid >> 6) * 8 + grp;
    if (n >= n_nodes) return;

    int s0 = rowstart[n], s1 = rowstart[n + 1];
    int trip = s1 - s0;

    float acc[8];
    #pragma unroll
    for (int q = 0; q < 8; ++q) acc[q] = 0.f;

    int myidx = 0;
    for (int it = 0; it < trip; ++it) {
        if ((it & 7) == 0) {
            int j = s0 + it + ch8;
            if (j >= s1) j = s1 - 1;       // clamped lanes never consumed
            myidx = (int)(csrp[j].y >> 16);
        }
        int s = __shfl(myidx, grp * 8 + (it & 7));
        uint4 u = *(const uint4*)(AJ2 + (size_t)s * 64 + ch8 * 8);
        acc[0] += bflo(u.x); acc[1] += bfhi(u.x);
        acc[2] += bflo(u.y); acc[3] += bfhi(u.y);
        acc[4] += bflo(u.z); acc[5] += bfhi(u.z);
        acc[6] += bflo(u.w); acc[7] += bfhi(u.w);
    }

    float deg = (float)(trip + 1);
    float4 e4 = eagg4[n];
    const float* aip = AI2 + (size_t)n * 64 + ch8 * 8;
    float4 aiA = *(const float4*)(aip);
    float4 aiB = *(const float4*)(aip + 4);
    uint4 su = *(const uint4*)(AJ2 + (size_t)n * 64 + ch8 * 8);
    float ajs[8] = { bflo(su.x), bfhi(su.x), bflo(su.y), bfhi(su.y),
                     bflo(su.z), bfhi(su.z), bflo(su.w), bfhi(su.w) };
    float4 bA = *(const float4*)(b2 + ch8 * 8);
    float4 bB = *(const float4*)(b2 + ch8 * 8 + 4);
    float av[8] = { aiA.x, aiA.y, aiA.z, aiA.w, aiB.x, aiB.y, aiB.z, aiB.w };
    float bv[8] = { bA.x, bA.y, bA.z, bA.w, bB.x, bB.y, bB.z, bB.w };
    float r[8];
    #pragma unroll
    for (int q = 0; q < 8; ++q) {
        int c = ch8 * 8 + q;
        float we = sWe[c * 3] * e4.x + sWe[c * 3 + 1] * e4.y + sWe[c * 3 + 2] * e4.z;
        r[q] = fmaxf(deg * (av[q] + bv[q]) + ajs[q] + we + acc[q], 0.f);
    }
    float pj[8];
    #pragma unroll
    for (int j = 0; j < 8; ++j) {
        float4 wA = *(const float4*)(sAB + j * 64 + ch8 * 8);
        float4 wB = *(const float4*)(sAB + j * 64 + ch8 * 8 + 4);
        pj[j] = r[0] * wA.x + r[1] * wA.y + r[2] * wA.z + r[3] * wA.w
              + r[4] * wB.x + r[5] * wB.y + r[6] * wB.z + r[7] * wB.w;
    }
    #pragma unroll
    for (int off = 1; off < 8; off <<= 1)
        #pragma unroll
        for (int j = 0; j < 8; ++j) pj[j] += __shfl_xor(pj[j], off);

    if (ch8 == 0) {
        *(float4*)(U + (size_t)n * 4) = make_float4(pj[0], pj[1], pj[2], pj[3]);
        *(float4*)(Z + (size_t)n * 4) = make_float4(pj[4], pj[5], pj[6], pj[7]);
    }
}

// ---- final: 8 lanes/node, 8 nodes/wave, sum Z[src] + log_softmax ----------

__global__ __launch_bounds__(256) void final_softmax(
    const float* __restrict__ U, const float* __restrict__ Z,
    const float4* __restrict__ eagg4, const int* __restrict__ rowstart,
    const uint2* __restrict__ csrp, const float* __restrict__ consts,
    float* __restrict__ out, int n_nodes)
{
    int wl = threadIdx.x & 63;
    int grp = wl >> 3, ch8 = wl & 7;
    int n = blockIdx.x * 32 + (threadIdx.x >> 6) * 8 + grp;
    if (n >= n_nodes) return;

    int s0 = rowstart[n], s1 = rowstart[n + 1];
    float ax = 0.f, ay = 0.f, az = 0.f, aw = 0.f;
    for (int i = s0 + ch8; i < s1; i += 8) {
        int s = (int)(csrp[i].y >> 16);
        float4 z = *(const float4*)(Z + (size_t)s * 4);
        ax += z.x; ay += z.y; az += z.z; aw += z.w;
    }
    #pragma unroll
    for (int off = 1; off < 8; off <<= 1) {
        ax += __shfl_xor(ax, off); ay += __shfl_xor(ay, off);
        az += __shfl_xor(az, off); aw += __shfl_xor(aw, off);
    }
    if (ch8 != 0) return;

    float deg = (float)(s1 - s0 + 1);
    float4 u = *(const float4*)(U + (size_t)n * 4);
    float4 zs = *(const float4*)(Z + (size_t)n * 4);   // self-loop term
    float4 e4 = eagg4[n];
    float av[4] = { ax + zs.x, ay + zs.y, az + zs.z, aw + zs.w };
    float uv[4] = { u.x, u.y, u.z, u.w };
    float lg[4];
    #pragma unroll
    for (int j = 0; j < 4; ++j) {
        lg[j] = deg * (uv[j] + consts[j]) + av[j] + consts[4 + j]
              + consts[8 + j * 3] * e4.x + consts[9 + j * 3] * e4.y
              + consts[10 + j * 3] * e4.z;
    }
    float m = fmaxf(fmaxf(lg[0], lg[1]), fmaxf(lg[2], lg[3]));
    float lse = logf(expf(lg[0] - m) + expf(lg[1] - m) + expf(lg[2] - m) + expf(lg[3] - m));
    *(float4*)(out + (size_t)n * 4) =
        make_float4(lg[0] - m - lse, lg[1] - m - lse, lg[2] - m - lse, lg[3] - m - lse);
}

// ---------------------------------------------------------------------------

extern "C" void kernel_launch(void* const* d_in, const int* in_sizes, int n_in,
                              void* d_out, int out_size, void* d_ws, size_t ws_size,
                              hipStream_t stream)
{
    const float* x    = (const float*)d_in[0];
    const int*   ei   = (const int*)  d_in[1];
    const float* ea   = (const float*)d_in[2];
    const float* W1   = (const float*)d_in[3];
    const float* b1   = (const float*)d_in[4];
    const float* W2   = (const float*)d_in[5];
    const float* b2   = (const float*)d_in[6];
    const float* W3   = (const float*)d_in[7];
    const float* b3   = (const float*)d_in[8];
    const float* Wc   = (const float*)d_in[9];
    const float* bc   = (const float*)d_in[10];
    float* out = (float*)d_out;

    const int N = in_sizes[0] / 3;
    const int E = in_sizes[1] / 2;

    char* ws = (char*)d_ws;
    size_t off = 0;
    int*    count    = (int*)(ws + off);            off = align256(off + (size_t)N * 4);
    int*    pos      = (int*)(ws + off);            off = align256(off + (size_t)E * 4);
    int*    rowstart = (int*)(ws + off);            off = align256(off + (size_t)(N + 1) * 4);
    uint2*  csrp     = (uint2*)(ws + off);          off = align256(off + (size_t)E * 8);
    int*    bsum     = (int*)(ws + off);            off = align256(off + 256);
    int*    bexcl    = (int*)(ws + off);            off = align256(off + 256);
    float*  AB       = (float*)(ws + off);          off = align256(off + 512 * 4);
    float*  consts   = (float*)(ws + off);          off = align256(off + 32 * 4);
    float4* eagg4    = (float4*)(ws + off);         off = align256(off + (size_t)N * 16);
    ushort_t* h1buf  = (ushort_t*)(ws + off);       off = align256(off + (size_t)N * 128 * 2);
    float*  AI2      = (float*)(ws + off);          off = align256(off + (size_t)N * 64 * 4);
    ushort_t* AJ2    = (ushort_t*)(ws + off);       off = align256(off + (size_t)N * 64 * 2);
    float*  Ubuf     = (float*)(ws + off);          off = align256(off + (size_t)N * 16);
    float*  Zbuf     = (float*)(ws + off);          off = align256(off + (size_t)N * 16);
    (void)ws_size;

    hipMemsetAsync(count, 0, (size_t)N * 4, stream);

    const int eb4 = ((E + 3) / 4 + 255) / 256;
    build_count<<<eb4, 256, 0, stream>>>(ei, count, pos, E);

    const int nb1 = (N + 1023) / 1024;
    scan_pass1<<<nb1, 256, 0, stream>>>(count, rowstart, bsum, N);
    scan_pass2<<<1, 64, 0, stream>>>(bsum, bexcl, nb1);
    scan_pass3<<<(N + 1 + 255) / 256, 256, 0, stream>>>(rowstart, bexcl, N);
    csr_scatter<<<eb4, 256, 0, stream>>>(ei, ea, pos, rowstart, csrp, E);

    prep_collapse<<<1, 256, 0, stream>>>(W3, b3, Wc, bc, AB, consts);

    const int gb = (N + 31) / 32;

    // layer 1 fused: aggregate x/ea per node + node-local matvec -> h1 (bf16)
    h1_fused<<<gb, 256, 0, stream>>>(x, W1, b1, rowstart, csrp, eagg4, h1buf, N);

    // layer 2: MFMA GEMM -> AI2 (fp32) + AJ2 (bf16); gather+relu+project
    gemm_mfma<<<(N + 63) / 64, 256, 0, stream>>>(h1buf, W2, AI2, AJ2, N);
    gather2<<<gb, 256, 0, stream>>>(AI2, AJ2, W2, b2, eagg4, rowstart, csrp, AB, Ubuf, Zbuf, N);

    // collapsed layer 3 + classifier + log_softmax
    final_softmax<<<gb, 256, 0, stream>>>(Ubuf, Zbuf, eagg4, rowstart, csrp, consts, out, N);
}